// Round 1
// baseline (3864.368 us; speedup 1.0000x reference)
//
#include <hip/hip_runtime.h>
#include <math.h>

// Problem constants
#define NB     4
#define NSEQ   4096
#define DMODEL 1024
#define NH     16
#define DHEAD  64
#define MFEAT  256
#define ROWS   (NB*NSEQ)     // 16384
#define BHDIM  (NB*NH)       // 64

#define DN        0.35355339059327373f   // 64^-0.25
#define RATIO     0.0625f                // 256^-0.5
#define HALF_DN2  0.0625f                // 0.5 * dn^2
#define EPSF      1.0e-4f

__device__ __forceinline__ float wave_max64(float v) {
  #pragma unroll
  for (int off = 32; off > 0; off >>= 1) v = fmaxf(v, __shfl_xor(v, off, 64));
  return v;
}
__device__ __forceinline__ float wave_sum64(float v) {
  #pragma unroll
  for (int off = 32; off > 0; off >>= 1) v += __shfl_xor(v, off, 64);
  return v;
}

// ---------------------------------------------------------------------------
// Tiled fp32 GEMM: C[M,N] = A[M,K] @ B[K,N] (+ bias). 64x64 tile, 256 thr.
// ---------------------------------------------------------------------------
template<bool BIAS>
__global__ __launch_bounds__(256) void gemm64(const float* __restrict__ A,
                                              const float* __restrict__ B,
                                              const float* __restrict__ bias,
                                              float* __restrict__ C,
                                              int Mr, int Nc, int Kd)
{
  __shared__ float As[16][68];   // As[k][m]
  __shared__ float Bs[16][68];   // Bs[k][n]
  const int tid = threadIdx.x;
  const int tx = tid & 15, ty = tid >> 4;
  const int row0 = blockIdx.y * 64, col0 = blockIdx.x * 64;

  float acc[4][4] = {};

  const int ar = tid >> 2;            // 0..63
  const int ac = (tid & 3) << 2;      // 0,4,8,12
  const int bk = tid >> 4;            // 0..15
  const int bc = (tid & 15) << 2;     // 0..60
  const float* Aptr = A + (size_t)(row0 + ar) * Kd + ac;
  const float* Bptr = B + (size_t)bk * Nc + col0 + bc;

  for (int k0 = 0; k0 < Kd; k0 += 16) {
    float4 av = *reinterpret_cast<const float4*>(Aptr + k0);
    float4 bv = *reinterpret_cast<const float4*>(Bptr + (size_t)k0 * Nc);
    __syncthreads();
    As[ac+0][ar] = av.x; As[ac+1][ar] = av.y; As[ac+2][ar] = av.z; As[ac+3][ar] = av.w;
    *reinterpret_cast<float4*>(&Bs[bk][bc]) = bv;
    __syncthreads();
    #pragma unroll
    for (int kk = 0; kk < 16; ++kk) {
      const float4 a = *reinterpret_cast<const float4*>(&As[kk][ty << 2]);
      const float4 b = *reinterpret_cast<const float4*>(&Bs[kk][tx << 2]);
      acc[0][0] += a.x*b.x; acc[0][1] += a.x*b.y; acc[0][2] += a.x*b.z; acc[0][3] += a.x*b.w;
      acc[1][0] += a.y*b.x; acc[1][1] += a.y*b.y; acc[1][2] += a.y*b.z; acc[1][3] += a.y*b.w;
      acc[2][0] += a.z*b.x; acc[2][1] += a.z*b.y; acc[2][2] += a.z*b.z; acc[2][3] += a.z*b.w;
      acc[3][0] += a.w*b.x; acc[3][1] += a.w*b.y; acc[3][2] += a.w*b.z; acc[3][3] += a.w*b.w;
    }
  }

  float4 bb = make_float4(0.f, 0.f, 0.f, 0.f);
  if (BIAS) bb = *reinterpret_cast<const float4*>(&bias[col0 + (tx << 2)]);
  #pragma unroll
  for (int i = 0; i < 4; ++i) {
    const int r = row0 + (ty << 2) + i;
    float4 o;
    o.x = acc[i][0] + bb.x; o.y = acc[i][1] + bb.y;
    o.z = acc[i][2] + bb.z; o.w = acc[i][3] + bb.w;
    *reinterpret_cast<float4*>(&C[(size_t)r * Nc + col0 + (tx << 2)]) = o;
  }
}

// ---------------------------------------------------------------------------
// Pass A: global max of dd_k = dn * (K @ P^T). 1024 blocks x 256 rows.
// Thread owns one feature m; P row in registers.
// ---------------------------------------------------------------------------
__global__ __launch_bounds__(256) void kmax_kernel(const float* __restrict__ Km,
                                                   const float* __restrict__ P,
                                                   float* __restrict__ part)
{
  const int tid  = threadIdx.x;
  const int bh   = blockIdx.x >> 4;   // 0..63
  const int tile = blockIdx.x & 15;   // 0..15 (256 rows each)
  const int b = bh >> 4, h = bh & 15;

  float p[64];
  #pragma unroll
  for (int d4 = 0; d4 < 64; d4 += 4) {
    const float4 pv = *reinterpret_cast<const float4*>(&P[tid * 64 + d4]);
    p[d4] = pv.x; p[d4+1] = pv.y; p[d4+2] = pv.z; p[d4+3] = pv.w;
  }

  __shared__ float ks[16][64];
  const int lr = tid >> 4;           // 0..15
  const int lc = (tid & 15) << 2;    // 0..60
  float mymax = -3.0e38f;
  const size_t base = ((size_t)b * NSEQ + tile * 256) * DMODEL + h * DHEAD;

  for (int s = 0; s < 256; s += 16) {
    const float4 kv = *reinterpret_cast<const float4*>(&Km[base + (size_t)(s + lr) * DMODEL + lc]);
    __syncthreads();
    *reinterpret_cast<float4*>(&ks[lr][lc]) = kv;
    __syncthreads();
    for (int r = 0; r < 16; ++r) {
      float dd = 0.f;
      #pragma unroll
      for (int d4 = 0; d4 < 64; d4 += 4) {
        const float4 kq = *reinterpret_cast<const float4*>(&ks[r][d4]);
        dd += kq.x*p[d4] + kq.y*p[d4+1] + kq.z*p[d4+2] + kq.w*p[d4+3];
      }
      mymax = fmaxf(mymax, dd);
    }
  }
  mymax *= DN;   // dn > 0: max commutes with positive scaling

  __shared__ float red[256];
  red[tid] = mymax;
  __syncthreads();
  for (int s = 128; s > 0; s >>= 1) {
    if (tid < s) red[tid] = fmaxf(red[tid], red[tid + s]);
    __syncthreads();
  }
  if (tid == 0) part[blockIdx.x] = red[0];
}

__global__ __launch_bounds__(256) void max_reduce_kernel(const float* __restrict__ part,
                                                         float* __restrict__ mx)
{
  const int tid = threadIdx.x;
  float v = -3.0e38f;
  for (int i = tid; i < 1024; i += 256) v = fmaxf(v, part[i]);
  __shared__ float red[256];
  red[tid] = v;
  __syncthreads();
  for (int s = 128; s > 0; s >>= 1) {
    if (tid < s) red[tid] = fmaxf(red[tid], red[tid + s]);
    __syncthreads();
  }
  if (tid == 0) mx[0] = red[0];
}

// ---------------------------------------------------------------------------
// Pass B (key side): kp on the fly -> accumulate k_cumsum[bh][m] and
// ctx[bh][m][dh]. 512 blocks = 64 bh x 8 chunks of 512 rows. Thread owns m.
// ---------------------------------------------------------------------------
__global__ __launch_bounds__(256) void kside_kernel(const float* __restrict__ Km,
                                                    const float* __restrict__ Vm,
                                                    const float* __restrict__ P,
                                                    const float* __restrict__ mxp,
                                                    float* __restrict__ ctx,
                                                    float* __restrict__ kcs)
{
  const int tid   = threadIdx.x;
  const int bh    = blockIdx.x >> 3;
  const int chunk = blockIdx.x & 7;
  const int b = bh >> 4, h = bh & 15;

  float p[64];
  #pragma unroll
  for (int d4 = 0; d4 < 64; d4 += 4) {
    const float4 pv = *reinterpret_cast<const float4*>(&P[tid * 64 + d4]);
    p[d4] = pv.x; p[d4+1] = pv.y; p[d4+2] = pv.z; p[d4+3] = pv.w;
  }
  const float mx = mxp[0];

  float acc[64] = {};
  float kcsum = 0.f;

  __shared__ float ks[16][64];
  __shared__ float vs[16][64];
  __shared__ float diag[16];
  const int lr = tid >> 4;
  const int lc = (tid & 15) << 2;
  const size_t rbase = (size_t)b * NSEQ + chunk * 512;

  for (int s = 0; s < 512; s += 16) {
    const size_t gb = (rbase + s + lr) * DMODEL + h * DHEAD + lc;
    const float4 kv = *reinterpret_cast<const float4*>(&Km[gb]);
    const float4 vv = *reinterpret_cast<const float4*>(&Vm[gb]);
    float ssq = kv.x*kv.x + kv.y*kv.y + kv.z*kv.z + kv.w*kv.w;
    ssq += __shfl_xor(ssq, 1, 64); ssq += __shfl_xor(ssq, 2, 64);
    ssq += __shfl_xor(ssq, 4, 64); ssq += __shfl_xor(ssq, 8, 64);
    __syncthreads();
    *reinterpret_cast<float4*>(&ks[lr][lc]) = kv;
    *reinterpret_cast<float4*>(&vs[lr][lc]) = vv;
    if ((tid & 15) == 0) diag[lr] = HALF_DN2 * ssq;
    __syncthreads();
    for (int r = 0; r < 16; ++r) {
      float dd = 0.f;
      #pragma unroll
      for (int d4 = 0; d4 < 64; d4 += 4) {
        const float4 kq = *reinterpret_cast<const float4*>(&ks[r][d4]);
        dd += kq.x*p[d4] + kq.y*p[d4+1] + kq.z*p[d4+2] + kq.w*p[d4+3];
      }
      const float kp = RATIO * (__expf(dd * DN - diag[r] - mx) + EPSF);
      kcsum += kp;
      #pragma unroll
      for (int d4 = 0; d4 < 64; d4 += 4) {
        const float4 vq = *reinterpret_cast<const float4*>(&vs[r][d4]);
        acc[d4]   += kp * vq.x; acc[d4+1] += kp * vq.y;
        acc[d4+2] += kp * vq.z; acc[d4+3] += kp * vq.w;
      }
    }
  }

  atomicAdd(&kcs[bh * MFEAT + tid], kcsum);
  float* cb = &ctx[((size_t)bh * MFEAT + tid) * DHEAD];
  #pragma unroll
  for (int d = 0; d < 64; ++d) atomicAdd(&cb[d], acc[d]);
}

// ---------------------------------------------------------------------------
// Pass C (query side): qp -> denom -> out_attn, fused. 8192 blocks =
// 64 bh x 128 tiles of 32 rows. Thread owns m for qp; then (dh, row-group)
// for the qp @ ctx product. Writes ATT in place over Q (disjoint regions).
// ---------------------------------------------------------------------------
__global__ __launch_bounds__(256) void qside_kernel(const float* __restrict__ Qm,
                                                    const float* __restrict__ P,
                                                    const float* __restrict__ kcs,
                                                    const float* __restrict__ ctx,
                                                    float* __restrict__ att)
{
  const int tid  = threadIdx.x;
  const int bh   = blockIdx.x >> 7;
  const int tile = blockIdx.x & 127;
  const int b = bh >> 4, h = bh & 15;

  __shared__ float qs[32][64];
  __shared__ float qp_s[32][256];
  __shared__ float diag_s[32], rmax_s[32], dinv_s[32];
  __shared__ float pmax[32][4], pden[32][4];

  float p[64];
  #pragma unroll
  for (int d4 = 0; d4 < 64; d4 += 4) {
    const float4 pv = *reinterpret_cast<const float4*>(&P[tid * 64 + d4]);
    p[d4] = pv.x; p[d4+1] = pv.y; p[d4+2] = pv.z; p[d4+3] = pv.w;
  }
  const float kc = kcs[bh * MFEAT + tid];

  const size_t qbase = ((size_t)b * NSEQ + tile * 32) * DMODEL + h * DHEAD;
  {
    const int lr = tid >> 3;          // 0..31
    const int lc = (tid & 7) << 3;    // 0..56
    const float4 q0 = *reinterpret_cast<const float4*>(&Qm[qbase + (size_t)lr * DMODEL + lc]);
    const float4 q1 = *reinterpret_cast<const float4*>(&Qm[qbase + (size_t)lr * DMODEL + lc + 4]);
    *reinterpret_cast<float4*>(&qs[lr][lc])     = q0;
    *reinterpret_cast<float4*>(&qs[lr][lc + 4]) = q1;
    float ssq = q0.x*q0.x + q0.y*q0.y + q0.z*q0.z + q0.w*q0.w
              + q1.x*q1.x + q1.y*q1.y + q1.z*q1.z + q1.w*q1.w;
    ssq += __shfl_xor(ssq, 1, 64); ssq += __shfl_xor(ssq, 2, 64);
    ssq += __shfl_xor(ssq, 4, 64);
    if ((tid & 7) == 0) diag_s[lr] = HALF_DN2 * ssq;
  }
  __syncthreads();

  // phase 1: dd[r] for this thread's m; per-row max across threads
  float dd[32];
  const int wv = tid >> 6, lane = tid & 63;
  #pragma unroll
  for (int r = 0; r < 32; ++r) {
    float s = 0.f;
    #pragma unroll
    for (int d4 = 0; d4 < 64; d4 += 4) {
      const float4 qv = *reinterpret_cast<const float4*>(&qs[r][d4]);
      s += qv.x*p[d4] + qv.y*p[d4+1] + qv.z*p[d4+2] + qv.w*p[d4+3];
    }
    dd[r] = s * DN;
    const float m = wave_max64(dd[r]);
    if (lane == 0) pmax[r][wv] = m;
  }
  __syncthreads();
  if (tid < 32) {
    rmax_s[tid] = fmaxf(fmaxf(pmax[tid][0], pmax[tid][1]),
                        fmaxf(pmax[tid][2], pmax[tid][3]));
  }
  __syncthreads();

  // phase 2: qp, denom
  #pragma unroll
  for (int r = 0; r < 32; ++r) {
    const float qp = RATIO * (__expf(dd[r] - diag_s[r] - rmax_s[r]) + EPSF);
    qp_s[r][tid] = qp;
    const float ds = wave_sum64(qp * kc);
    if (lane == 0) pden[r][wv] = ds;
  }
  __syncthreads();
  if (tid < 32) {
    dinv_s[tid] = 1.0f / (pden[tid][0] + pden[tid][1] + pden[tid][2] + pden[tid][3]);
  }
  __syncthreads();

  // phase 3: out[r][dh] = (sum_m qp[r][m] * ctx[m][dh]) * dinv[r]
  const int dh = tid & 63;
  const int rg = tid >> 6;       // row group 0..3 -> rows rg*8..rg*8+7
  float oa[8] = {};
  const float* cb = &ctx[(size_t)bh * MFEAT * DHEAD + dh];
  #pragma unroll 8
  for (int m = 0; m < 256; ++m) {
    const float c = cb[(size_t)m * DHEAD];
    #pragma unroll
    for (int i = 0; i < 8; ++i) oa[i] += qp_s[rg * 8 + i][m] * c;
  }
  #pragma unroll
  for (int i = 0; i < 8; ++i) {
    const int r = rg * 8 + i;
    att[qbase + (size_t)r * DMODEL + dh] = oa[i] * dinv_s[r];
  }
}

// ---------------------------------------------------------------------------
extern "C" void kernel_launch(void* const* d_in, const int* in_sizes, int n_in,
                              void* d_out, int out_size, void* d_ws, size_t ws_size,
                              hipStream_t stream)
{
  const float* x  = (const float*)d_in[0];
  const float* Wq = (const float*)d_in[1];
  const float* Wk = (const float*)d_in[2];
  const float* Wv = (const float*)d_in[3];
  const float* Wo = (const float*)d_in[4];
  const float* bo = (const float*)d_in[5];
  const float* P  = (const float*)d_in[6];
  float* out = (float*)d_out;
  float* ws  = (float*)d_ws;

  // ws layout (floats)
  float* Q    = ws;                       // 16M  (later aliased as ATT)
  float* K    = ws + 16777216;            // 16M
  float* V    = ws + 33554432;            // 16M
  float* CTX  = ws + 50331648;            // 64*256*64 = 1,048,576
  float* KCS  = CTX + 1048576;            // 64*256   = 16,384
  float* PART = KCS + 16384;              // 1024
  float* MX   = PART + 1024;              // 1

  hipMemsetAsync(CTX, 0, (1048576 + 16384) * sizeof(float), stream);

  dim3 gemmGrid(DMODEL / 64, ROWS / 64);  // (16, 256)
  gemm64<false><<<gemmGrid, 256, 0, stream>>>(x, Wq, nullptr, Q, ROWS, DMODEL, DMODEL);
  gemm64<false><<<gemmGrid, 256, 0, stream>>>(x, Wk, nullptr, K, ROWS, DMODEL, DMODEL);
  gemm64<false><<<gemmGrid, 256, 0, stream>>>(x, Wv, nullptr, V, ROWS, DMODEL, DMODEL);

  kmax_kernel<<<1024, 256, 0, stream>>>(K, P, PART);
  max_reduce_kernel<<<1, 256, 0, stream>>>(PART, MX);
  kside_kernel<<<512, 256, 0, stream>>>(K, V, P, MX, CTX, KCS);
  qside_kernel<<<8192, 256, 0, stream>>>(Q, P, KCS, CTX, Q /* ATT in place */);

  gemm64<true><<<gemmGrid, 256, 0, stream>>>(Q, Wo, bo, out, ROWS, DMODEL, DMODEL);
}

// Round 2
// 1414.048 us; speedup vs baseline: 2.7328x; 2.7328x over previous
//
#include <hip/hip_runtime.h>
#include <math.h>

#define NB 4
#define NSEQ 4096
#define DM 1024
#define NHEAD 16
#define DHD 64
#define MF 256
#define ROWS 16384

#define DN 0.35355339059327373f
#define RATIO 0.0625f
#define HALF_DN2 0.0625f
#define EPSF 1.0e-4f

typedef __attribute__((ext_vector_type(4))) float f32x4;
typedef __attribute__((ext_vector_type(8))) short short8;
typedef __attribute__((ext_vector_type(8))) __bf16 bf16x8;

__device__ __forceinline__ unsigned short f2bf(float f) {
  unsigned int u = __builtin_bit_cast(unsigned int, f);
  u += 0x7FFFu + ((u >> 16) & 1u);
  return (unsigned short)(u >> 16);
}

__device__ __forceinline__ f32x4 mfma16(short8 a, short8 b, f32x4 c) {
  return __builtin_amdgcn_mfma_f32_16x16x32_bf16(
      __builtin_bit_cast(bf16x8, a), __builtin_bit_cast(bf16x8, b), c, 0, 0, 0);
}

__device__ __forceinline__ void glds16(const void* g, void* l) {
  __builtin_amdgcn_global_load_lds(
      (const __attribute__((address_space(1))) unsigned int*)g,
      (__attribute__((address_space(3))) unsigned int*)l, 16, 0, 0);
}

__device__ __forceinline__ float wave_max64(float v) {
  #pragma unroll
  for (int off = 32; off > 0; off >>= 1) v = fmaxf(v, __shfl_xor(v, off, 64));
  return v;
}
__device__ __forceinline__ float wave_sum64(float v) {
  #pragma unroll
  for (int off = 32; off > 0; off >>= 1) v += __shfl_xor(v, off, 64);
  return v;
}

// ---------------------------------------------------------------------------
// Weight transpose-cast: Wt[n][k] = bf16(W[k][n]).  grid (16,16), 256 thr.
// ---------------------------------------------------------------------------
__global__ __launch_bounds__(256) void wtrans(const float* __restrict__ W,
                                              unsigned short* __restrict__ Wt)
{
  __shared__ float ts[64][68];
  const int tid = threadIdx.x;
  const int k0 = blockIdx.y * 64, n0 = blockIdx.x * 64;
  const int r = tid >> 4, c4 = (tid & 15) * 4;
  #pragma unroll
  for (int i = 0; i < 4; ++i) {
    float4 v = *(const float4*)&W[(size_t)(k0 + r + i * 16) * DM + n0 + c4];
    *(float4*)&ts[r + i * 16][c4] = v;
  }
  __syncthreads();
  #pragma unroll
  for (int i = 0; i < 4; ++i) {
    const int n = r + i * 16;
    ushort4 o;
    o.x = f2bf(ts[c4 + 0][n]); o.y = f2bf(ts[c4 + 1][n]);
    o.z = f2bf(ts[c4 + 2][n]); o.w = f2bf(ts[c4 + 3][n]);
    *(ushort4*)&Wt[(size_t)(n0 + n) * DM + k0 + c4] = o;
  }
}

// ---------------------------------------------------------------------------
// bf16 MFMA GEMM: C[M=16384,N=1024] = A[M,K=1024] @ Bt[N,K]^T.
// 128x128 tile, BK=32, 4 waves (2x2), granule-XOR swizzled LDS.
// AF32: A is fp32, convert during staging. EPI: 0=C fp32, 1=+bias, 2=VT bf16.
// ---------------------------------------------------------------------------
template<bool AF32, int EPI>
__global__ __launch_bounds__(256) void gemm_k(const float* __restrict__ Af,
                                              const unsigned short* __restrict__ Ab,
                                              const unsigned short* __restrict__ Bt,
                                              const float* __restrict__ bias,
                                              float* __restrict__ C,
                                              unsigned short* __restrict__ VT)
{
  constexpr int K = DM, N = DM;
  __shared__ unsigned short As[128 * 32];
  __shared__ unsigned short Bs[128 * 32];

  const int tid = threadIdx.x;
  const int l = tid & 63, w = tid >> 6;
  const int ll = l & 15, lh = l >> 4;
  const int wr = w >> 1, wc = w & 1;

  const int bid = blockIdx.x;
  const int swz = (bid & 7) * ((int)gridDim.x >> 3) + (bid >> 3);
  const int bm = swz >> 3, bn = swz & 7;
  const int row0 = bm * 128, col0 = bn * 128;

  // B staging: slots pb = w*128 + {0,64} + l   (glds, 16B/lane)
  const int pb0 = w * 128 + l, pb1 = pb0 + 64;
  const int brow0 = pb0 >> 2, bkq0 = (pb0 & 3) ^ ((brow0 >> 1) & 3);
  const int brow1 = pb1 >> 2, bkq1 = (pb1 & 3) ^ ((brow1 >> 1) & 3);
  const unsigned short* bsrc0 = Bt + (size_t)(col0 + brow0) * K + bkq0 * 8;
  const unsigned short* bsrc1 = Bt + (size_t)(col0 + brow1) * K + bkq1 * 8;
  unsigned short* bdst0 = &Bs[(size_t)(w * 128) * 8];
  unsigned short* bdst1 = &Bs[(size_t)(w * 128 + 64) * 8];

  // A staging
  const int pa0 = tid, pa1 = tid + 256;                 // AF32 path slots
  const int arow0 = pa0 >> 2, akq0 = (pa0 & 3) ^ ((arow0 >> 1) & 3);
  const int arow1 = pa1 >> 2, akq1 = (pa1 & 3) ^ ((arow1 >> 1) & 3);
  const float* afs0 = nullptr; const float* afs1 = nullptr;
  const unsigned short* abs0_ = nullptr; const unsigned short* abs1_ = nullptr;
  if constexpr (AF32) {
    afs0 = Af + (size_t)(row0 + arow0) * K + akq0 * 8;
    afs1 = Af + (size_t)(row0 + arow1) * K + akq1 * 8;
  } else {
    abs0_ = Ab + (size_t)(row0 + brow0) * K + bkq0 * 8;
    abs1_ = Ab + (size_t)(row0 + brow1) * K + bkq1 * 8;
  }

  // fragment read offsets (ushort index), constant over K
  int aoff[4], boff[4];
  #pragma unroll
  for (int mt = 0; mt < 4; ++mt) {
    const int r = wr * 64 + mt * 16 + ll;
    aoff[mt] = (r * 4 + (lh ^ ((r >> 1) & 3))) * 8;
  }
  #pragma unroll
  for (int nt = 0; nt < 4; ++nt) {
    const int r = wc * 64 + nt * 16 + ll;
    boff[nt] = (r * 4 + (lh ^ ((r >> 1) & 3))) * 8;
  }

  f32x4 acc[4][4];
  #pragma unroll
  for (int i = 0; i < 4; ++i)
    #pragma unroll
    for (int j = 0; j < 4; ++j) acc[i][j] = (f32x4){0.f, 0.f, 0.f, 0.f};

  for (int k0 = 0; k0 < K; k0 += 32) {
    __syncthreads();
    if constexpr (AF32) {
      const float4 u0 = *(const float4*)(afs0 + k0);
      const float4 u1 = *(const float4*)(afs0 + k0 + 4);
      const float4 v0 = *(const float4*)(afs1 + k0);
      const float4 v1 = *(const float4*)(afs1 + k0 + 4);
      short8 s0, s1;
      s0[0] = f2bf(u0.x); s0[1] = f2bf(u0.y); s0[2] = f2bf(u0.z); s0[3] = f2bf(u0.w);
      s0[4] = f2bf(u1.x); s0[5] = f2bf(u1.y); s0[6] = f2bf(u1.z); s0[7] = f2bf(u1.w);
      s1[0] = f2bf(v0.x); s1[1] = f2bf(v0.y); s1[2] = f2bf(v0.z); s1[3] = f2bf(v0.w);
      s1[4] = f2bf(v1.x); s1[5] = f2bf(v1.y); s1[6] = f2bf(v1.z); s1[7] = f2bf(v1.w);
      *(short8*)&As[(size_t)pa0 * 8] = s0;
      *(short8*)&As[(size_t)pa1 * 8] = s1;
    } else {
      glds16(abs0_ + k0, &As[(size_t)(w * 128) * 8]);
      glds16(abs1_ + k0, &As[(size_t)(w * 128 + 64) * 8]);
    }
    glds16(bsrc0 + k0, bdst0);
    glds16(bsrc1 + k0, bdst1);
    __syncthreads();

    short8 av[4], bv[4];
    #pragma unroll
    for (int mt = 0; mt < 4; ++mt) av[mt] = *(const short8*)&As[aoff[mt]];
    #pragma unroll
    for (int nt = 0; nt < 4; ++nt) bv[nt] = *(const short8*)&Bs[boff[nt]];
    #pragma unroll
    for (int mt = 0; mt < 4; ++mt)
      #pragma unroll
      for (int nt = 0; nt < 4; ++nt)
        acc[mt][nt] = mfma16(av[mt], bv[nt], acc[mt][nt]);
  }

  if constexpr (EPI <= 1) {
    #pragma unroll
    for (int mt = 0; mt < 4; ++mt) {
      #pragma unroll
      for (int nt = 0; nt < 4; ++nt) {
        const int row = row0 + wr * 64 + mt * 16 + lh * 4;
        const int col = col0 + wc * 64 + nt * 16 + ll;
        const float bv_ = (EPI == 1) ? bias[col] : 0.f;
        #pragma unroll
        for (int j = 0; j < 4; ++j)
          C[(size_t)(row + j) * N + col] = acc[mt][nt][j] + bv_;
      }
    }
  } else {
    // VT[bh][dh][n] bf16 scatter (acc j-index = consecutive n)
    #pragma unroll
    for (int mt = 0; mt < 4; ++mt) {
      #pragma unroll
      for (int nt = 0; nt < 4; ++nt) {
        const int rg = row0 + wr * 64 + mt * 16 + lh * 4;
        const int cg = col0 + wc * 64 + nt * 16 + ll;
        const int b = rg >> 12, n = rg & 4095;
        const int h = cg >> 6, dh = cg & 63;
        ushort4 o;
        o.x = f2bf(acc[mt][nt][0]); o.y = f2bf(acc[mt][nt][1]);
        o.z = f2bf(acc[mt][nt][2]); o.w = f2bf(acc[mt][nt][3]);
        *(ushort4*)&VT[(((size_t)b * 16 + h) * 64 + dh) * 4096 + n] = o;
      }
    }
  }
}

// ---------------------------------------------------------------------------
// Pass A: global max of dd_k = dn * (K @ P^T).  (unchanged from round 1)
// ---------------------------------------------------------------------------
__global__ __launch_bounds__(256) void kmax_kernel(const float* __restrict__ Km,
                                                   const float* __restrict__ P,
                                                   float* __restrict__ part)
{
  const int tid = threadIdx.x;
  const int bh = blockIdx.x >> 4;
  const int tile = blockIdx.x & 15;
  const int b = bh >> 4, h = bh & 15;

  float p[64];
  #pragma unroll
  for (int d4 = 0; d4 < 64; d4 += 4) {
    const float4 pv = *(const float4*)&P[tid * 64 + d4];
    p[d4] = pv.x; p[d4 + 1] = pv.y; p[d4 + 2] = pv.z; p[d4 + 3] = pv.w;
  }

  __shared__ float ks[16][64];
  const int lr = tid >> 4;
  const int lc = (tid & 15) << 2;
  float mymax = -3.0e38f;
  const size_t base = ((size_t)b * NSEQ + tile * 256) * DM + h * DHD;

  for (int s = 0; s < 256; s += 16) {
    const float4 kv = *(const float4*)&Km[base + (size_t)(s + lr) * DM + lc];
    __syncthreads();
    *(float4*)&ks[lr][lc] = kv;
    __syncthreads();
    for (int r = 0; r < 16; ++r) {
      float dd = 0.f;
      #pragma unroll
      for (int d4 = 0; d4 < 64; d4 += 4) {
        const float4 kq = *(const float4*)&ks[r][d4];
        dd += kq.x * p[d4] + kq.y * p[d4 + 1] + kq.z * p[d4 + 2] + kq.w * p[d4 + 3];
      }
      mymax = fmaxf(mymax, dd);
    }
  }
  mymax *= DN;

  __shared__ float red[256];
  red[tid] = mymax;
  __syncthreads();
  for (int s = 128; s > 0; s >>= 1) {
    if (tid < s) red[tid] = fmaxf(red[tid], red[tid + s]);
    __syncthreads();
  }
  if (tid == 0) part[blockIdx.x] = red[0];
}

__global__ __launch_bounds__(256) void max_reduce_kernel(const float* __restrict__ part,
                                                         float* __restrict__ mx)
{
  const int tid = threadIdx.x;
  float v = -3.0e38f;
  for (int i = tid; i < 1024; i += 256) v = fmaxf(v, part[i]);
  __shared__ float red[256];
  red[tid] = v;
  __syncthreads();
  for (int s = 128; s > 0; s >>= 1) {
    if (tid < s) red[tid] = fmaxf(red[tid], red[tid + s]);
    __syncthreads();
  }
  if (tid == 0) mx[0] = red[0];
}

// ---------------------------------------------------------------------------
// Pass B v2: kp fp32 on the fly -> pack bf16 -> MFMA ctx accumulation.
// grid 512 = 64 bh x 8 chunks (512 rows); 256 thr (4 waves).
// ---------------------------------------------------------------------------
__global__ __launch_bounds__(256) void kside2(const float* __restrict__ Kf,
                                              const unsigned short* __restrict__ VT,
                                              const float* __restrict__ P,
                                              const float* __restrict__ mxp,
                                              float* __restrict__ ctx,
                                              float* __restrict__ kcs)
{
  const int tid = threadIdx.x;
  const int l = tid & 63, w = tid >> 6;
  const int ll = l & 15, lh = l >> 4;
  const int bh = blockIdx.x >> 3, chunk = blockIdx.x & 7;
  const int b = bh >> 4, h = bh & 15;

  __shared__ float ks[64][68];
  __shared__ float diag_s[64];
  __shared__ unsigned short kpT[256 * 64];   // [m][r-granule XOR-swizzled]
  __shared__ unsigned short vt_s[64 * 72];   // [dh][72] (64 used, pad 8)

  float p[64];
  #pragma unroll
  for (int d4 = 0; d4 < 64; d4 += 4) {
    const float4 pv = *(const float4*)&P[tid * 64 + d4];
    p[d4] = pv.x; p[d4 + 1] = pv.y; p[d4 + 2] = pv.z; p[d4 + 3] = pv.w;
  }
  const float mx = mxp[0];
  float kcsum = 0.f;

  f32x4 acc[4][4];
  #pragma unroll
  for (int i = 0; i < 4; ++i)
    #pragma unroll
    for (int j = 0; j < 4; ++j) acc[i][j] = (f32x4){0.f, 0.f, 0.f, 0.f};

  const int n0c = chunk * 512;
  for (int t = 0; t < 8; ++t) {
    const int n0 = n0c + t * 64;
    __syncthreads();
    {   // stage K tile fp32 + diag
      const int r = tid >> 2, q = tid & 3;
      const float* src = &Kf[((size_t)b * NSEQ + n0 + r) * DM + h * DHD + q * 16];
      const float4 a0 = *(const float4*)(src + 0);
      const float4 a1 = *(const float4*)(src + 4);
      const float4 a2 = *(const float4*)(src + 8);
      const float4 a3 = *(const float4*)(src + 12);
      float ssq = a0.x*a0.x + a0.y*a0.y + a0.z*a0.z + a0.w*a0.w
                + a1.x*a1.x + a1.y*a1.y + a1.z*a1.z + a1.w*a1.w
                + a2.x*a2.x + a2.y*a2.y + a2.z*a2.z + a2.w*a2.w
                + a3.x*a3.x + a3.y*a3.y + a3.z*a3.z + a3.w*a3.w;
      ssq += __shfl_xor(ssq, 1, 64); ssq += __shfl_xor(ssq, 2, 64);
      *(float4*)&ks[r][q * 16 + 0]  = a0;
      *(float4*)&ks[r][q * 16 + 4]  = a1;
      *(float4*)&ks[r][q * 16 + 8]  = a2;
      *(float4*)&ks[r][q * 16 + 12] = a3;
      if (q == 0) diag_s[r] = HALF_DN2 * ssq;
    }
    {   // stage VT tile bf16: [dh][r]
      const int dh = tid >> 2, rq = (tid & 3) * 16;
      const unsigned short* src = &VT[((size_t)bh * 64 + dh) * NSEQ + n0 + rq];
      const short8 v0 = *(const short8*)src;
      const short8 v1 = *(const short8*)(src + 8);
      *(short8*)&vt_s[dh * 72 + rq] = v0;
      *(short8*)&vt_s[dh * 72 + rq + 8] = v1;
    }
    __syncthreads();

    // dd/kp for m = tid (fp32), pack bf16 pairs, granule-swizzled LDS write
    for (int r8 = 0; r8 < 8; ++r8) {
      unsigned int kq_[4];
      #pragma unroll
      for (int jj = 0; jj < 4; ++jj) {
        float ddv[2];
        #pragma unroll
        for (int hh = 0; hh < 2; ++hh) {
          const int rr = r8 * 8 + jj * 2 + hh;
          float s = 0.f;
          #pragma unroll
          for (int d4 = 0; d4 < 16; ++d4) {
            const float4 kv = *(const float4*)&ks[rr][d4 * 4];
            s += kv.x * p[d4*4] + kv.y * p[d4*4+1] + kv.z * p[d4*4+2] + kv.w * p[d4*4+3];
          }
          ddv[hh] = s;
        }
        const int rr0 = r8 * 8 + jj * 2;
        const float kp0 = RATIO * (__expf(ddv[0] * DN - diag_s[rr0]     - mx) + EPSF);
        const float kp1 = RATIO * (__expf(ddv[1] * DN - diag_s[rr0 + 1] - mx) + EPSF);
        kcsum += kp0 + kp1;
        kq_[jj] = (unsigned)f2bf(kp0) | ((unsigned)f2bf(kp1) << 16);
      }
      *(uint4*)&kpT[(size_t)tid * 64 + ((r8 ^ (tid & 7)) << 3)] =
          make_uint4(kq_[0], kq_[1], kq_[2], kq_[3]);
    }
    __syncthreads();

    // MFMA: ctx[m][dh] += kpT[m][r] * V[r][dh]; wave owns m-range w*64..+64
    #pragma unroll
    for (int rs = 0; rs < 2; ++rs) {
      short8 av[4], bv[4];
      #pragma unroll
      for (int mt = 0; mt < 4; ++mt) {
        const int m = w * 64 + mt * 16 + ll;
        const int g = rs * 4 + lh;
        av[mt] = *(const short8*)&kpT[(size_t)m * 64 + ((g ^ (m & 7)) << 3)];
      }
      #pragma unroll
      for (int dt = 0; dt < 4; ++dt) {
        const int dh = dt * 16 + ll;
        bv[dt] = *(const short8*)&vt_s[dh * 72 + rs * 32 + lh * 8];
      }
      #pragma unroll
      for (int mt = 0; mt < 4; ++mt)
        #pragma unroll
        for (int dt = 0; dt < 4; ++dt)
          acc[mt][dt] = mfma16(av[mt], bv[dt], acc[mt][dt]);
    }
  }

  atomicAdd(&kcs[bh * MF + tid], kcsum);
  #pragma unroll
  for (int mt = 0; mt < 4; ++mt) {
    #pragma unroll
    for (int dt = 0; dt < 4; ++dt) {
      #pragma unroll
      for (int j = 0; j < 4; ++j) {
        const int m = w * 64 + mt * 16 + lh * 4 + j;
        const int dh = dt * 16 + ll;
        atomicAdd(&ctx[((size_t)bh * MF + m) * DHD + dh], acc[mt][dt][j]);
      }
    }
  }
}

// ---------------------------------------------------------------------------
// Pass C (query side): qp -> denom -> out_attn (bf16 out).
// ---------------------------------------------------------------------------
__global__ __launch_bounds__(256) void qside_kernel(const float* __restrict__ Qm,
                                                    const float* __restrict__ P,
                                                    const float* __restrict__ kcs,
                                                    const float* __restrict__ ctx,
                                                    unsigned short* __restrict__ attb)
{
  const int tid = threadIdx.x;
  const int bh = blockIdx.x >> 7;
  const int tile = blockIdx.x & 127;
  const int b = bh >> 4, h = bh & 15;

  __shared__ float qs[32][64];
  __shared__ float qp_s[32][256];
  __shared__ float diag_s[32], rmax_s[32], dinv_s[32];
  __shared__ float pmax[32][4], pden[32][4];

  float p[64];
  #pragma unroll
  for (int d4 = 0; d4 < 64; d4 += 4) {
    const float4 pv = *(const float4*)&P[tid * 64 + d4];
    p[d4] = pv.x; p[d4 + 1] = pv.y; p[d4 + 2] = pv.z; p[d4 + 3] = pv.w;
  }
  const float kc = kcs[bh * MF + tid];

  const size_t qbase = ((size_t)b * NSEQ + tile * 32) * DM + h * DHD;
  {
    const int lr = tid >> 3;
    const int lc = (tid & 7) << 3;
    const float4 q0 = *(const float4*)&Qm[qbase + (size_t)lr * DM + lc];
    const float4 q1 = *(const float4*)&Qm[qbase + (size_t)lr * DM + lc + 4];
    *(float4*)&qs[lr][lc] = q0;
    *(float4*)&qs[lr][lc + 4] = q1;
    float ssq = q0.x*q0.x + q0.y*q0.y + q0.z*q0.z + q0.w*q0.w
              + q1.x*q1.x + q1.y*q1.y + q1.z*q1.z + q1.w*q1.w;
    ssq += __shfl_xor(ssq, 1, 64); ssq += __shfl_xor(ssq, 2, 64);
    ssq += __shfl_xor(ssq, 4, 64);
    if ((tid & 7) == 0) diag_s[lr] = HALF_DN2 * ssq;
  }
  __syncthreads();

  float dd[32];
  const int wv = tid >> 6, lane = tid & 63;
  #pragma unroll
  for (int r = 0; r < 32; ++r) {
    float s = 0.f;
    #pragma unroll
    for (int d4 = 0; d4 < 64; d4 += 4) {
      const float4 qv = *(const float4*)&qs[r][d4];
      s += qv.x * p[d4] + qv.y * p[d4 + 1] + qv.z * p[d4 + 2] + qv.w * p[d4 + 3];
    }
    dd[r] = s * DN;
    const float m = wave_max64(dd[r]);
    if (lane == 0) pmax[r][wv] = m;
  }
  __syncthreads();
  if (tid < 32) {
    rmax_s[tid] = fmaxf(fmaxf(pmax[tid][0], pmax[tid][1]),
                        fmaxf(pmax[tid][2], pmax[tid][3]));
  }
  __syncthreads();

  #pragma unroll
  for (int r = 0; r < 32; ++r) {
    const float qp = RATIO * (__expf(dd[r] - diag_s[r] - rmax_s[r]) + EPSF);
    qp_s[r][tid] = qp;
    const float ds = wave_sum64(qp * kc);
    if (lane == 0) pden[r][wv] = ds;
  }
  __syncthreads();
  if (tid < 32) {
    dinv_s[tid] = 1.0f / (pden[tid][0] + pden[tid][1] + pden[tid][2] + pden[tid][3]);
  }
  __syncthreads();

  const int dh = tid & 63;
  const int rg = tid >> 6;
  float oa[8] = {};
  const float* cb = &ctx[(size_t)bh * MF * DHD + dh];
  #pragma unroll 8
  for (int m = 0; m < 256; ++m) {
    const float c = cb[(size_t)m * DHD];
    #pragma unroll
    for (int i = 0; i < 8; ++i) oa[i] += qp_s[rg * 8 + i][m] * c;
  }
  #pragma unroll
  for (int i = 0; i < 8; ++i) {
    const int r = rg * 8 + i;
    attb[qbase + (size_t)r * DM + dh] = f2bf(oa[i] * dinv_s[r]);
  }
}

// ---------------------------------------------------------------------------
extern "C" void kernel_launch(void* const* d_in, const int* in_sizes, int n_in,
                              void* d_out, int out_size, void* d_ws, size_t ws_size,
                              hipStream_t stream)
{
  const float* x  = (const float*)d_in[0];
  const float* Wq = (const float*)d_in[1];
  const float* Wk = (const float*)d_in[2];
  const float* Wv = (const float*)d_in[3];
  const float* Wo = (const float*)d_in[4];
  const float* bo = (const float*)d_in[5];
  const float* P  = (const float*)d_in[6];
  float* out = (float*)d_out;
  float* ws  = (float*)d_ws;

  // ws layout (floats)
  float* Q   = ws;                               // 16777216
  float* KF  = ws + 16777216;                    // 16777216 (ATTb overlays)
  unsigned short* VT  = (unsigned short*)(ws + 33554432);  // 16777216 ushorts
  unsigned short* WT  = (unsigned short*)(ws + 41943040);  // 4 x 1048576 ushorts
  float* CTX  = ws + 44040192;                   // 1048576
  float* KCS  = ws + 45088768;                   // 16384
  float* PART = ws + 45105152;                   // 1024
  float* MX   = ws + 45106176;                   // 1
  unsigned short* ATTB = (unsigned short*)KF;

  unsigned short* Wqt = WT;
  unsigned short* Wkt = WT + 1048576;
  unsigned short* Wvt = WT + 2097152;
  unsigned short* Wot = WT + 3145728;

  hipMemsetAsync(CTX, 0, (1048576 + 16384) * sizeof(float), stream);

  dim3 tg(16, 16);
  wtrans<<<tg, 256, 0, stream>>>(Wq, Wqt);
  wtrans<<<tg, 256, 0, stream>>>(Wk, Wkt);
  wtrans<<<tg, 256, 0, stream>>>(Wv, Wvt);
  wtrans<<<tg, 256, 0, stream>>>(Wo, Wot);

  gemm_k<true, 0><<<1024, 256, 0, stream>>>(x, nullptr, Wqt, nullptr, Q, nullptr);
  gemm_k<true, 0><<<1024, 256, 0, stream>>>(x, nullptr, Wkt, nullptr, KF, nullptr);
  gemm_k<true, 2><<<1024, 256, 0, stream>>>(x, nullptr, Wvt, nullptr, nullptr, VT);

  kmax_kernel<<<1024, 256, 0, stream>>>(KF, P, PART);
  max_reduce_kernel<<<1, 256, 0, stream>>>(PART, MX);
  kside2<<<512, 256, 0, stream>>>(KF, VT, P, MX, CTX, KCS);
  qside_kernel<<<8192, 256, 0, stream>>>(Q, P, KCS, CTX, ATTB);

  gemm_k<false, 1><<<1024, 256, 0, stream>>>(nullptr, ATTB, Wot, bo, out, nullptr);
}

// Round 3
// 768.110 us; speedup vs baseline: 5.0310x; 1.8409x over previous
//
#include <hip/hip_runtime.h>
#include <math.h>

#define NB 4
#define NSEQ 4096
#define DM 1024
#define NHEAD 16
#define DHD 64
#define MF 256
#define ROWS 16384

#define DN 0.35355339059327373f
#define RATIO 0.0625f
#define HALF_DN2 0.0625f
#define EPSF 1.0e-4f

typedef __attribute__((ext_vector_type(4))) float f32x4;
typedef __attribute__((ext_vector_type(8))) short short8;
typedef __attribute__((ext_vector_type(8))) __bf16 bf16x8;
typedef unsigned short ushort_t;

__device__ __forceinline__ unsigned short f2bf(float f) {
  unsigned int u = __builtin_bit_cast(unsigned int, f);
  u += 0x7FFFu + ((u >> 16) & 1u);
  return (unsigned short)(u >> 16);
}
__device__ __forceinline__ float bf2f(unsigned short h) {
  unsigned int u = ((unsigned int)h) << 16;
  return __builtin_bit_cast(float, u);
}

__device__ __forceinline__ f32x4 mfma16(short8 a, short8 b, f32x4 c) {
  return __builtin_amdgcn_mfma_f32_16x16x32_bf16(
      __builtin_bit_cast(bf16x8, a), __builtin_bit_cast(bf16x8, b), c, 0, 0, 0);
}

__device__ __forceinline__ void glds16(const void* g, void* l) {
  __builtin_amdgcn_global_load_lds(
      (const __attribute__((address_space(1))) unsigned int*)g,
      (__attribute__((address_space(3))) unsigned int*)l, 16, 0, 0);
}

// ---------------------------------------------------------------------------
// Weight transpose-cast: Wt[n][k] = bf16(W[k][n]).
// ---------------------------------------------------------------------------
__global__ __launch_bounds__(256) void wtrans(const float* __restrict__ W,
                                              ushort_t* __restrict__ Wt)
{
  __shared__ float ts[64][68];
  const int tid = threadIdx.x;
  const int k0 = blockIdx.y * 64, n0 = blockIdx.x * 64;
  const int r = tid >> 4, c4 = (tid & 15) * 4;
  #pragma unroll
  for (int i = 0; i < 4; ++i) {
    float4 v = *(const float4*)&W[(size_t)(k0 + r + i * 16) * DM + n0 + c4];
    *(float4*)&ts[r + i * 16][c4] = v;
  }
  __syncthreads();
  #pragma unroll
  for (int i = 0; i < 4; ++i) {
    const int n = r + i * 16;
    ushort4 o;
    o.x = f2bf(ts[c4 + 0][n]); o.y = f2bf(ts[c4 + 1][n]);
    o.z = f2bf(ts[c4 + 2][n]); o.w = f2bf(ts[c4 + 3][n]);
    *(ushort4*)&Wt[(size_t)(n0 + n) * DM + k0 + c4] = o;
  }
}

// ---------------------------------------------------------------------------
// P split: PHI/PLO bf16 [256][64]
// ---------------------------------------------------------------------------
__global__ __launch_bounds__(256) void psplit(const float* __restrict__ P,
                                              ushort_t* __restrict__ PHI,
                                              ushort_t* __restrict__ PLO)
{
  const int i = blockIdx.x * 256 + threadIdx.x;   // 16384 total
  const float v = P[i];
  const unsigned short h = f2bf(v);
  PHI[i] = h;
  PLO[i] = f2bf(v - bf2f(h));
}

// ---------------------------------------------------------------------------
// bf16 MFMA GEMM: C[16384,1024] = A @ Bt^T. 128x128, BK=32.
// EPI: 0=C fp32, 1=C fp32+bias, 2=VT bf16 [bh][dh][n], 3=hi/lo bf16 split.
// ---------------------------------------------------------------------------
template<bool AF32, int EPI>
__global__ __launch_bounds__(256) void gemm_k(const float* __restrict__ Af,
                                              const ushort_t* __restrict__ Ab,
                                              const ushort_t* __restrict__ Bt,
                                              const float* __restrict__ bias,
                                              float* __restrict__ C,
                                              ushort_t* __restrict__ VT,
                                              ushort_t* __restrict__ OH,
                                              ushort_t* __restrict__ OL)
{
  constexpr int K = DM, N = DM;
  __shared__ ushort_t As[128 * 32];
  __shared__ ushort_t Bs[128 * 32];

  const int tid = threadIdx.x;
  const int l = tid & 63, w = tid >> 6;
  const int ll = l & 15, lh = l >> 4;
  const int wr = w >> 1, wc = w & 1;

  const int bid = blockIdx.x;
  const int swz = (bid & 7) * ((int)gridDim.x >> 3) + (bid >> 3);
  const int bm = swz >> 3, bn = swz & 7;
  const int row0 = bm * 128, col0 = bn * 128;

  const int pb0 = w * 128 + l, pb1 = pb0 + 64;
  const int brow0 = pb0 >> 2, bkq0 = (pb0 & 3) ^ ((brow0 >> 1) & 3);
  const int brow1 = pb1 >> 2, bkq1 = (pb1 & 3) ^ ((brow1 >> 1) & 3);
  const ushort_t* bsrc0 = Bt + (size_t)(col0 + brow0) * K + bkq0 * 8;
  const ushort_t* bsrc1 = Bt + (size_t)(col0 + brow1) * K + bkq1 * 8;
  ushort_t* bdst0 = &Bs[(size_t)(w * 128) * 8];
  ushort_t* bdst1 = &Bs[(size_t)(w * 128 + 64) * 8];

  const int pa0 = tid, pa1 = tid + 256;
  const int arow0 = pa0 >> 2, akq0 = (pa0 & 3) ^ ((arow0 >> 1) & 3);
  const int arow1 = pa1 >> 2, akq1 = (pa1 & 3) ^ ((arow1 >> 1) & 3);
  const float* afs0 = nullptr; const float* afs1 = nullptr;
  const ushort_t* abs0_ = nullptr; const ushort_t* abs1_ = nullptr;
  if constexpr (AF32) {
    afs0 = Af + (size_t)(row0 + arow0) * K + akq0 * 8;
    afs1 = Af + (size_t)(row0 + arow1) * K + akq1 * 8;
  } else {
    abs0_ = Ab + (size_t)(row0 + brow0) * K + bkq0 * 8;
    abs1_ = Ab + (size_t)(row0 + brow1) * K + bkq1 * 8;
  }

  int aoff[4], boff[4];
  #pragma unroll
  for (int mt = 0; mt < 4; ++mt) {
    const int r = wr * 64 + mt * 16 + ll;
    aoff[mt] = (r * 4 + (lh ^ ((r >> 1) & 3))) * 8;
  }
  #pragma unroll
  for (int nt = 0; nt < 4; ++nt) {
    const int r = wc * 64 + nt * 16 + ll;
    boff[nt] = (r * 4 + (lh ^ ((r >> 1) & 3))) * 8;
  }

  f32x4 acc[4][4];
  #pragma unroll
  for (int i = 0; i < 4; ++i)
    #pragma unroll
    for (int j = 0; j < 4; ++j) acc[i][j] = (f32x4){0.f, 0.f, 0.f, 0.f};

  for (int k0 = 0; k0 < K; k0 += 32) {
    __syncthreads();
    if constexpr (AF32) {
      const float4 u0 = *(const float4*)(afs0 + k0);
      const float4 u1 = *(const float4*)(afs0 + k0 + 4);
      const float4 v0 = *(const float4*)(afs1 + k0);
      const float4 v1 = *(const float4*)(afs1 + k0 + 4);
      short8 s0, s1;
      s0[0] = f2bf(u0.x); s0[1] = f2bf(u0.y); s0[2] = f2bf(u0.z); s0[3] = f2bf(u0.w);
      s0[4] = f2bf(u1.x); s0[5] = f2bf(u1.y); s0[6] = f2bf(u1.z); s0[7] = f2bf(u1.w);
      s1[0] = f2bf(v0.x); s1[1] = f2bf(v0.y); s1[2] = f2bf(v0.z); s1[3] = f2bf(v0.w);
      s1[4] = f2bf(v1.x); s1[5] = f2bf(v1.y); s1[6] = f2bf(v1.z); s1[7] = f2bf(v1.w);
      *(short8*)&As[(size_t)pa0 * 8] = s0;
      *(short8*)&As[(size_t)pa1 * 8] = s1;
    } else {
      glds16(abs0_ + k0, &As[(size_t)(w * 128) * 8]);
      glds16(abs1_ + k0, &As[(size_t)(w * 128 + 64) * 8]);
    }
    glds16(bsrc0 + k0, bdst0);
    glds16(bsrc1 + k0, bdst1);
    __syncthreads();

    short8 av[4], bv[4];
    #pragma unroll
    for (int mt = 0; mt < 4; ++mt) av[mt] = *(const short8*)&As[aoff[mt]];
    #pragma unroll
    for (int nt = 0; nt < 4; ++nt) bv[nt] = *(const short8*)&Bs[boff[nt]];
    #pragma unroll
    for (int mt = 0; mt < 4; ++mt)
      #pragma unroll
      for (int nt = 0; nt < 4; ++nt)
        acc[mt][nt] = mfma16(av[mt], bv[nt], acc[mt][nt]);
  }

  if constexpr (EPI <= 1) {
    #pragma unroll
    for (int mt = 0; mt < 4; ++mt) {
      #pragma unroll
      for (int nt = 0; nt < 4; ++nt) {
        const int row = row0 + wr * 64 + mt * 16 + lh * 4;
        const int col = col0 + wc * 64 + nt * 16 + ll;
        const float bv_ = (EPI == 1) ? bias[col] : 0.f;
        #pragma unroll
        for (int j = 0; j < 4; ++j)
          C[(size_t)(row + j) * N + col] = acc[mt][nt][j] + bv_;
      }
    }
  } else if constexpr (EPI == 2) {
    #pragma unroll
    for (int mt = 0; mt < 4; ++mt) {
      #pragma unroll
      for (int nt = 0; nt < 4; ++nt) {
        const int rg = row0 + wr * 64 + mt * 16 + lh * 4;
        const int cg = col0 + wc * 64 + nt * 16 + ll;
        const int b = rg >> 12, n = rg & 4095;
        const int h = cg >> 6, dh = cg & 63;
        ushort4 o;
        o.x = f2bf(acc[mt][nt][0]); o.y = f2bf(acc[mt][nt][1]);
        o.z = f2bf(acc[mt][nt][2]); o.w = f2bf(acc[mt][nt][3]);
        *(ushort4*)&VT[(((size_t)b * 16 + h) * 64 + dh) * 4096 + n] = o;
      }
    }
  } else {   // EPI == 3: hi/lo split bf16, row-major
    #pragma unroll
    for (int mt = 0; mt < 4; ++mt) {
      #pragma unroll
      for (int nt = 0; nt < 4; ++nt) {
        const int row = row0 + wr * 64 + mt * 16 + lh * 4;
        const int col = col0 + wc * 64 + nt * 16 + ll;
        #pragma unroll
        for (int j = 0; j < 4; ++j) {
          const float v = acc[mt][nt][j];
          const unsigned short hh = f2bf(v);
          OH[(size_t)(row + j) * N + col] = hh;
          OL[(size_t)(row + j) * N + col] = f2bf(v - bf2f(hh));
        }
      }
    }
  }
}

// ---------------------------------------------------------------------------
// kmax: global max of dn*(K·P^T) via split-bf16 MFMA.
// grid 1024 = 64 bh x 16 tiles (256 rows). 256 thr.
// ---------------------------------------------------------------------------
__global__ __launch_bounds__(256) void kmax2(const ushort_t* __restrict__ KHI,
                                             const ushort_t* __restrict__ KLO,
                                             const ushort_t* __restrict__ PHI,
                                             const ushort_t* __restrict__ PLO,
                                             float* __restrict__ part)
{
  const int tid = threadIdx.x;
  const int l = tid & 63, w = tid >> 6;
  const int ll = l & 15, lh = l >> 4;
  const int bh = blockIdx.x >> 4, rt = blockIdx.x & 15;
  const int b = bh >> 4, h = bh & 15;

  float mymax = -3.0e38f;
  for (int sub = 0; sub < 4; ++sub) {
    const int n = rt * 256 + sub * 64 + w * 16 + ll;
    const ushort_t* kh = KHI + ((size_t)(b * NSEQ + n) * DM + h * DHD);
    const ushort_t* kl = KLO + ((size_t)(b * NSEQ + n) * DM + h * DHD);
    short8 ah[2], al[2];
    #pragma unroll
    for (int ks = 0; ks < 2; ++ks) {
      ah[ks] = *(const short8*)(kh + ks * 32 + lh * 8);
      al[ks] = *(const short8*)(kl + ks * 32 + lh * 8);
    }
    for (int mt = 0; mt < 16; ++mt) {
      f32x4 acc = (f32x4){0.f, 0.f, 0.f, 0.f};
      #pragma unroll
      for (int ks = 0; ks < 2; ++ks) {
        const short8 bh_ = *(const short8*)(PHI + (mt * 16 + ll) * DHD + ks * 32 + lh * 8);
        const short8 bl_ = *(const short8*)(PLO + (mt * 16 + ll) * DHD + ks * 32 + lh * 8);
        acc = mfma16(ah[ks], bh_, acc);
        acc = mfma16(ah[ks], bl_, acc);
        acc = mfma16(al[ks], bh_, acc);
      }
      mymax = fmaxf(mymax, fmaxf(fmaxf(acc[0], acc[1]), fmaxf(acc[2], acc[3])));
    }
  }
  mymax *= DN;

  __shared__ float red[256];
  red[tid] = mymax;
  __syncthreads();
  for (int s = 128; s > 0; s >>= 1) {
    if (tid < s) red[tid] = fmaxf(red[tid], red[tid + s]);
    __syncthreads();
  }
  if (tid == 0) part[blockIdx.x] = red[0];
}

__global__ __launch_bounds__(256) void max_reduce_kernel(const float* __restrict__ part,
                                                         float* __restrict__ mx)
{
  const int tid = threadIdx.x;
  float v = -3.0e38f;
  for (int i = tid; i < 1024; i += 256) v = fmaxf(v, part[i]);
  __shared__ float red[256];
  red[tid] = v;
  __syncthreads();
  for (int s = 128; s > 0; s >>= 1) {
    if (tid < s) red[tid] = fmaxf(red[tid], red[tid + s]);
    __syncthreads();
  }
  if (tid == 0) mx[0] = red[0];
}

// ---------------------------------------------------------------------------
// kside3: split-MFMA dd -> kp (fp32 exp) -> bf16 kpT -> MFMA ctx accumulation.
// grid 512 = 64 bh x 8 chunks (512 rows). 256 thr (4 waves).
// ---------------------------------------------------------------------------
__global__ __launch_bounds__(256) void kside3(const ushort_t* __restrict__ KHI,
                                              const ushort_t* __restrict__ KLO,
                                              const ushort_t* __restrict__ VT,
                                              const ushort_t* __restrict__ PHI,
                                              const ushort_t* __restrict__ PLO,
                                              const float* __restrict__ mxp,
                                              float* __restrict__ ctx,
                                              float* __restrict__ kcs)
{
  const int tid = threadIdx.x;
  const int l = tid & 63, w = tid >> 6;
  const int ll = l & 15, lh = l >> 4;
  const int bh = blockIdx.x >> 3, chunk = blockIdx.x & 7;
  const int b = bh >> 4, h = bh & 15;

  __shared__ ushort_t kpT[256 * 64];   // [m][64 n-local], XOR-swizzled
  __shared__ float diag_s[64];

  const float mx = mxp[0];
  float kc_part[16];
  #pragma unroll
  for (int i = 0; i < 16; ++i) kc_part[i] = 0.f;

  f32x4 accv[4][4];
  #pragma unroll
  for (int i = 0; i < 4; ++i)
    #pragma unroll
    for (int j = 0; j < 4; ++j) accv[i][j] = (f32x4){0.f, 0.f, 0.f, 0.f};

  for (int sub = 0; sub < 8; ++sub) {
    const int nl0 = sub * 64;
    const int n = chunk * 512 + nl0 + w * 16 + ll;
    const ushort_t* kh = KHI + ((size_t)(b * NSEQ + n) * DM + h * DHD);
    const ushort_t* kl = KLO + ((size_t)(b * NSEQ + n) * DM + h * DHD);
    short8 ah[2], al[2];
    #pragma unroll
    for (int ks = 0; ks < 2; ++ks) {
      ah[ks] = *(const short8*)(kh + ks * 32 + lh * 8);
      al[ks] = *(const short8*)(kl + ks * 32 + lh * 8);
    }
    float ssq = 0.f;
    #pragma unroll
    for (int ks = 0; ks < 2; ++ks)
      #pragma unroll
      for (int e = 0; e < 8; ++e) {
        const float kv = bf2f((unsigned short)ah[ks][e]) + bf2f((unsigned short)al[ks][e]);
        ssq += kv * kv;
      }
    ssq += __shfl_xor(ssq, 16, 64);
    ssq += __shfl_xor(ssq, 32, 64);

    __syncthreads();                          // prev PV done with kpT/diag
    if (lh == 0) diag_s[w * 16 + ll] = HALF_DN2 * ssq;
    __syncthreads();

    float dgv[4];
    #pragma unroll
    for (int j = 0; j < 4; ++j) dgv[j] = diag_s[w * 16 + lh * 4 + j];

    for (int mt = 0; mt < 16; ++mt) {
      f32x4 acc = (f32x4){0.f, 0.f, 0.f, 0.f};
      #pragma unroll
      for (int ks = 0; ks < 2; ++ks) {
        const short8 bh_ = *(const short8*)(PHI + (mt * 16 + ll) * DHD + ks * 32 + lh * 8);
        const short8 bl_ = *(const short8*)(PLO + (mt * 16 + ll) * DHD + ks * 32 + lh * 8);
        acc = mfma16(ah[ks], bh_, acc);
        acc = mfma16(ah[ks], bl_, acc);
        acc = mfma16(al[ks], bh_, acc);
      }
      const int m = mt * 16 + ll;
      ushort4 o;
      {
        const unsigned short b0 = f2bf(RATIO * (__expf(acc[0] * DN - dgv[0] - mx) + EPSF));
        const unsigned short b1 = f2bf(RATIO * (__expf(acc[1] * DN - dgv[1] - mx) + EPSF));
        const unsigned short b2 = f2bf(RATIO * (__expf(acc[2] * DN - dgv[2] - mx) + EPSF));
        const unsigned short b3 = f2bf(RATIO * (__expf(acc[3] * DN - dgv[3] - mx) + EPSF));
        kc_part[mt] += bf2f(b0) + bf2f(b1) + bf2f(b2) + bf2f(b3);
        o.x = b0; o.y = b1; o.z = b2; o.w = b3;
      }
      const int idx = (m * 64 + w * 16 + lh * 4) ^ ((m & 7) << 3);
      *(ushort4*)&kpT[idx] = o;
    }
    __syncthreads();

    // PV: ctx[m][dh] += kp[m][n] * V[n][dh]
    short8 av[4][2];
    #pragma unroll
    for (int mt = 0; mt < 4; ++mt) {
      const int m = w * 64 + mt * 16 + ll;
      #pragma unroll
      for (int ks = 0; ks < 2; ++ks) {
        const int idx = (m * 64 + ks * 32 + lh * 8) ^ ((m & 7) << 3);
        av[mt][ks] = *(const short8*)&kpT[idx];
      }
    }
    #pragma unroll
    for (int dt = 0; dt < 4; ++dt) {
      const ushort_t* vb = VT + ((size_t)bh * 64 + dt * 16 + ll) * NSEQ + chunk * 512 + nl0;
      #pragma unroll
      for (int ks = 0; ks < 2; ++ks) {
        const short8 bv = *(const short8*)(vb + ks * 32 + lh * 8);
        #pragma unroll
        for (int mt = 0; mt < 4; ++mt)
          accv[mt][dt] = mfma16(av[mt][ks], bv, accv[mt][dt]);
      }
    }
  }

  #pragma unroll
  for (int mt = 0; mt < 16; ++mt) {
    float s = kc_part[mt];
    s += __shfl_xor(s, 16, 64);
    s += __shfl_xor(s, 32, 64);
    if (lh == 0) atomicAdd(&kcs[bh * MF + mt * 16 + ll], s);
  }
  #pragma unroll
  for (int mt = 0; mt < 4; ++mt)
    #pragma unroll
    for (int dt = 0; dt < 4; ++dt)
      #pragma unroll
      for (int j = 0; j < 4; ++j) {
        const int m = w * 64 + mt * 16 + lh * 4 + j;
        const int dh = dt * 16 + ll;
        atomicAdd(&ctx[((size_t)bh * MF + m) * DHD + dh], accv[mt][dt][j]);
      }
}

// ---------------------------------------------------------------------------
// ctx fp32 [bh][m][dh] -> CTH/CTL bf16 [bh][dh][m]. grid 256 = 64 bh x 4 m-chunks.
// ---------------------------------------------------------------------------
__global__ __launch_bounds__(256) void ctx2bf(const float* __restrict__ ctx,
                                              ushort_t* __restrict__ CTH,
                                              ushort_t* __restrict__ CTL)
{
  __shared__ float ts[64][68];
  const int tid = threadIdx.x;
  const int bh = blockIdx.x >> 2, mc = blockIdx.x & 3;
  const int r = tid >> 4, c4 = (tid & 15) * 4;
  #pragma unroll
  for (int i = 0; i < 4; ++i) {
    const int m = mc * 64 + r + i * 16;
    *(float4*)&ts[r + i * 16][c4] = *(const float4*)&ctx[((size_t)bh * MF + m) * DHD + c4];
  }
  __syncthreads();
  #pragma unroll
  for (int i = 0; i < 4; ++i) {
    const int dh = r + i * 16;
    ushort4 oh, ol;
    #pragma unroll
    for (int k = 0; k < 4; ++k) {
      const float v = ts[c4 + k][dh];
      const unsigned short hh = f2bf(v);
      const unsigned short hl = f2bf(v - bf2f(hh));
      ((unsigned short*)&oh)[k] = hh;
      ((unsigned short*)&ol)[k] = hl;
    }
    const size_t o = ((size_t)bh * 64 + dh) * MF + mc * 64 + c4;
    *(ushort4*)&CTH[o] = oh;
    *(ushort4*)&CTL[o] = ol;
  }
}

// ---------------------------------------------------------------------------
// qside4: split-MFMA dd -> row softmax -> bf16 qpN -> PV MFMA -> bf16 ATT.
// grid 4096 = 64 bh x 64 tiles (64 rows). 256 thr (4 waves).
// ---------------------------------------------------------------------------
__global__ __launch_bounds__(256) void qside4(const ushort_t* __restrict__ QHI,
                                              const ushort_t* __restrict__ QLO,
                                              const ushort_t* __restrict__ PHI,
                                              const ushort_t* __restrict__ PLO,
                                              const float* __restrict__ kcs,
                                              const ushort_t* __restrict__ CTH,
                                              const ushort_t* __restrict__ CTL,
                                              ushort_t* __restrict__ attb)
{
  const int tid = threadIdx.x;
  const int l = tid & 63, w = tid >> 6;
  const int ll = l & 15, lh = l >> 4;
  const int bh = blockIdx.x >> 6, qt = blockIdx.x & 63;
  const int b = bh >> 4, h = bh & 15;

  __shared__ ushort_t qpN[64 * 256];   // [n-local][m], XOR-swizzled
  __shared__ float diag_s[64];
  __shared__ float kcs_s[256];

  kcs_s[tid] = kcs[bh * MF + tid];

  const int n = qt * 64 + w * 16 + ll;
  const ushort_t* qh = QHI + ((size_t)(b * NSEQ + n) * DM + h * DHD);
  const ushort_t* ql = QLO + ((size_t)(b * NSEQ + n) * DM + h * DHD);
  short8 ah[2], al[2];
  #pragma unroll
  for (int ks = 0; ks < 2; ++ks) {
    ah[ks] = *(const short8*)(qh + ks * 32 + lh * 8);
    al[ks] = *(const short8*)(ql + ks * 32 + lh * 8);
  }
  float ssq = 0.f;
  #pragma unroll
  for (int ks = 0; ks < 2; ++ks)
    #pragma unroll
    for (int e = 0; e < 8; ++e) {
      const float qv = bf2f((unsigned short)ah[ks][e]) + bf2f((unsigned short)al[ks][e]);
      ssq += qv * qv;
    }
  ssq += __shfl_xor(ssq, 16, 64);
  ssq += __shfl_xor(ssq, 32, 64);
  if (lh == 0) diag_s[w * 16 + ll] = HALF_DN2 * ssq;
  __syncthreads();

  float dgv[4];
  #pragma unroll
  for (int j = 0; j < 4; ++j) dgv[j] = diag_s[w * 16 + lh * 4 + j];

  // dd for all 256 m
  f32x4 dd[16];
  for (int mt = 0; mt < 16; ++mt) {
    f32x4 acc = (f32x4){0.f, 0.f, 0.f, 0.f};
    #pragma unroll
    for (int ks = 0; ks < 2; ++ks) {
      const short8 bh_ = *(const short8*)(PHI + (mt * 16 + ll) * DHD + ks * 32 + lh * 8);
      const short8 bl_ = *(const short8*)(PLO + (mt * 16 + ll) * DHD + ks * 32 + lh * 8);
      acc = mfma16(ah[ks], bh_, acc);
      acc = mfma16(ah[ks], bl_, acc);
      acc = mfma16(al[ks], bh_, acc);
    }
    #pragma unroll
    for (int j = 0; j < 4; ++j) acc[j] *= DN;
    dd[mt] = acc;
  }

  // per-row max over 256 m
  float rmx[4];
  #pragma unroll
  for (int j = 0; j < 4; ++j) rmx[j] = -3.0e38f;
  #pragma unroll
  for (int mt = 0; mt < 16; ++mt)
    #pragma unroll
    for (int j = 0; j < 4; ++j) rmx[j] = fmaxf(rmx[j], dd[mt][j]);
  #pragma unroll
  for (int j = 0; j < 4; ++j) {
    rmx[j] = fmaxf(rmx[j], __shfl_xor(rmx[j], 1, 64));
    rmx[j] = fmaxf(rmx[j], __shfl_xor(rmx[j], 2, 64));
    rmx[j] = fmaxf(rmx[j], __shfl_xor(rmx[j], 4, 64));
    rmx[j] = fmaxf(rmx[j], __shfl_xor(rmx[j], 8, 64));
  }

  // qp (fp32 exp, bf16-rounded), denominator from the SAME rounded values
  float den[4] = {0.f, 0.f, 0.f, 0.f};
  for (int mt = 0; mt < 16; ++mt) {
    const int m = mt * 16 + ll;
    const float kcv = kcs_s[m];
    #pragma unroll
    for (int j = 0; j < 4; ++j) {
      const float qp = RATIO * (__expf(dd[mt][j] - dgv[j] - rmx[j]) + EPSF);
      const unsigned short qb = f2bf(qp);
      den[j] += bf2f(qb) * kcv;
      const int nloc = w * 16 + lh * 4 + j;
      qpN[(nloc * 256 + m) ^ ((nloc & 7) << 3)] = qb;
    }
  }
  float dinv[4];
  #pragma unroll
  for (int j = 0; j < 4; ++j) {
    den[j] += __shfl_xor(den[j], 1, 64);
    den[j] += __shfl_xor(den[j], 2, 64);
    den[j] += __shfl_xor(den[j], 4, 64);
    den[j] += __shfl_xor(den[j], 8, 64);
    dinv[j] = 1.0f / den[j];
  }
  __syncthreads();

  // PV: out[n][dh] = sum_m qp[n][m] * ctx[m][dh]  (ctx split hi/lo)
  f32x4 accp[4];
  #pragma unroll
  for (int dt = 0; dt < 4; ++dt) accp[dt] = (f32x4){0.f, 0.f, 0.f, 0.f};
  const int na = w * 16 + ll;
  for (int ks2 = 0; ks2 < 8; ++ks2) {
    const short8 av = *(const short8*)&qpN[(na * 256 + ks2 * 32 + lh * 8) ^ ((na & 7) << 3)];
    #pragma unroll
    for (int dt = 0; dt < 4; ++dt) {
      const size_t cb = ((size_t)bh * 64 + dt * 16 + ll) * MF + ks2 * 32 + lh * 8;
      const short8 bvh = *(const short8*)(CTH + cb);
      const short8 bvl = *(const short8*)(CTL + cb);
      accp[dt] = mfma16(av, bvh, accp[dt]);
      accp[dt] = mfma16(av, bvl, accp[dt]);
    }
  }

  // epilogue: ATT bf16
  #pragma unroll
  for (int dt = 0; dt < 4; ++dt)
    #pragma unroll
    for (int j = 0; j < 4; ++j) {
      const int row = b * NSEQ + qt * 64 + w * 16 + lh * 4 + j;
      const int col = h * DHD + dt * 16 + ll;
      attb[(size_t)row * DM + col] = f2bf(accp[dt][j] * dinv[j]);
    }
}

// ---------------------------------------------------------------------------
extern "C" void kernel_launch(void* const* d_in, const int* in_sizes, int n_in,
                              void* d_out, int out_size, void* d_ws, size_t ws_size,
                              hipStream_t stream)
{
  const float* x  = (const float*)d_in[0];
  const float* Wq = (const float*)d_in[1];
  const float* Wk = (const float*)d_in[2];
  const float* Wv = (const float*)d_in[3];
  const float* Wo = (const float*)d_in[4];
  const float* bo = (const float*)d_in[5];
  const float* P  = (const float*)d_in[6];
  float* out = (float*)d_out;

  char* wp = (char*)d_ws;
  ushort_t* QHI = (ushort_t*)wp;  wp += 33554432;
  ushort_t* QLO = (ushort_t*)wp;  wp += 33554432;
  ushort_t* KHI = (ushort_t*)wp;  wp += 33554432;   // ATTB overlays later
  ushort_t* KLO = (ushort_t*)wp;  wp += 33554432;
  ushort_t* VT  = (ushort_t*)wp;  wp += 33554432;
  ushort_t* Wqt = (ushort_t*)wp;  wp += 2097152;
  ushort_t* Wkt = (ushort_t*)wp;  wp += 2097152;
  ushort_t* Wvt = (ushort_t*)wp;  wp += 2097152;
  ushort_t* Wot = (ushort_t*)wp;  wp += 2097152;
  ushort_t* PHI = (ushort_t*)wp;  wp += 32768;
  ushort_t* PLO = (ushort_t*)wp;  wp += 32768;
  float*    CTX = (float*)wp;     wp += 4194304;
  float*    KCS = (float*)wp;     wp += 65536;
  ushort_t* CTH = (ushort_t*)wp;  wp += 2097152;
  ushort_t* CTL = (ushort_t*)wp;  wp += 2097152;
  float*    PART = (float*)wp;    wp += 4096;
  float*    MX  = (float*)wp;     wp += 256;
  ushort_t* ATTB = KHI;

  hipMemsetAsync(CTX, 0, 4194304 + 65536, stream);   // CTX + KCS contiguous

  dim3 tg(16, 16);
  wtrans<<<tg, 256, 0, stream>>>(Wq, Wqt);
  wtrans<<<tg, 256, 0, stream>>>(Wk, Wkt);
  wtrans<<<tg, 256, 0, stream>>>(Wv, Wvt);
  wtrans<<<tg, 256, 0, stream>>>(Wo, Wot);
  psplit<<<64, 256, 0, stream>>>(P, PHI, PLO);

  gemm_k<true, 3><<<1024, 256, 0, stream>>>(x, nullptr, Wqt, nullptr, nullptr, nullptr, QHI, QLO);
  gemm_k<true, 3><<<1024, 256, 0, stream>>>(x, nullptr, Wkt, nullptr, nullptr, nullptr, KHI, KLO);
  gemm_k<true, 2><<<1024, 256, 0, stream>>>(x, nullptr, Wvt, nullptr, nullptr, VT, nullptr, nullptr);

  kmax2<<<1024, 256, 0, stream>>>(KHI, KLO, PHI, PLO, PART);
  max_reduce_kernel<<<1, 256, 0, stream>>>(PART, MX);
  kside3<<<512, 256, 0, stream>>>(KHI, KLO, VT, PHI, PLO, MX, CTX, KCS);
  ctx2bf<<<256, 256, 0, stream>>>(CTX, CTH, CTL);
  qside4<<<4096, 256, 0, stream>>>(QHI, QLO, PHI, PLO, KCS, CTH, CTL, ATTB);

  gemm_k<false, 1><<<1024, 256, 0, stream>>>(nullptr, ATTB, Wot, bo, out, nullptr, nullptr, nullptr);
}

// Round 4
// 534.471 us; speedup vs baseline: 7.2303x; 1.4371x over previous
//
#include <hip/hip_runtime.h>
#include <math.h>

#define NB 4
#define NSEQ 4096
#define DM 1024
#define NHEAD 16
#define DHD 64
#define MF 256
#define ROWS 16384

#define DN 0.35355339059327373f
#define RATIO 0.0625f
#define HALF_DN2 0.0625f
#define EPSF 1.0e-4f

typedef __attribute__((ext_vector_type(4))) float f32x4;
typedef __attribute__((ext_vector_type(8))) short short8;
typedef __attribute__((ext_vector_type(4))) short short4v;
typedef __attribute__((ext_vector_type(8))) __bf16 bf16x8;
typedef unsigned short ushort_t;

__device__ __forceinline__ unsigned short f2bf(float f) {
  unsigned int u = __builtin_bit_cast(unsigned int, f);
  u += 0x7FFFu + ((u >> 16) & 1u);
  return (unsigned short)(u >> 16);
}
__device__ __forceinline__ float bf2f(unsigned short h) {
  unsigned int u = ((unsigned int)h) << 16;
  return __builtin_bit_cast(float, u);
}

__device__ __forceinline__ f32x4 mfma16(short8 a, short8 b, f32x4 c) {
  return __builtin_amdgcn_mfma_f32_16x16x32_bf16(
      __builtin_bit_cast(bf16x8, a), __builtin_bit_cast(bf16x8, b), c, 0, 0, 0);
}

// 16x16x16 bf16 MFMA (K=16): A/B = 4 bf16 per lane, k = 4*(lane>>4)+e
__device__ __forceinline__ f32x4 mfma16x16(short4v a, short4v b, f32x4 c) {
#if __has_builtin(__builtin_amdgcn_mfma_f32_16x16x16bf16_1k)
  return __builtin_amdgcn_mfma_f32_16x16x16bf16_1k(a, b, c, 0, 0, 0);
#elif __has_builtin(__builtin_amdgcn_mfma_f32_16x16x16_bf16)
  typedef __attribute__((ext_vector_type(4))) __bf16 bf16x4;
  return __builtin_amdgcn_mfma_f32_16x16x16_bf16(
      __builtin_bit_cast(bf16x4, a), __builtin_bit_cast(bf16x4, b), c, 0, 0, 0);
#else
  asm volatile("s_nop 1\n\t"
               "v_mfma_f32_16x16x16_bf16 %0, %1, %2, %0\n\t"
               "s_nop 7"
               : "+v"(c) : "v"(a), "v"(b));
  return c;
#endif
}

__device__ __forceinline__ void glds16(const void* g, void* l) {
  __builtin_amdgcn_global_load_lds(
      (const __attribute__((address_space(1))) unsigned int*)g,
      (__attribute__((address_space(3))) unsigned int*)l, 16, 0, 0);
}

// ---------------------------------------------------------------------------
// Weight transpose-cast: Wt[n][k] = bf16(W[k][n]).
// ---------------------------------------------------------------------------
__global__ __launch_bounds__(256) void wtrans(const float* __restrict__ W,
                                              ushort_t* __restrict__ Wt)
{
  __shared__ float ts[64][68];
  const int tid = threadIdx.x;
  const int k0 = blockIdx.y * 64, n0 = blockIdx.x * 64;
  const int r = tid >> 4, c4 = (tid & 15) * 4;
  #pragma unroll
  for (int i = 0; i < 4; ++i) {
    float4 v = *(const float4*)&W[(size_t)(k0 + r + i * 16) * DM + n0 + c4];
    *(float4*)&ts[r + i * 16][c4] = v;
  }
  __syncthreads();
  #pragma unroll
  for (int i = 0; i < 4; ++i) {
    const int n = r + i * 16;
    ushort4 o;
    o.x = f2bf(ts[c4 + 0][n]); o.y = f2bf(ts[c4 + 1][n]);
    o.z = f2bf(ts[c4 + 2][n]); o.w = f2bf(ts[c4 + 3][n]);
    *(ushort4*)&Wt[(size_t)(n0 + n) * DM + k0 + c4] = o;
  }
}

// ---------------------------------------------------------------------------
// P split: PHI/PLO bf16 [256][64]
// ---------------------------------------------------------------------------
__global__ __launch_bounds__(256) void psplit(const float* __restrict__ P,
                                              ushort_t* __restrict__ PHI,
                                              ushort_t* __restrict__ PLO)
{
  const int i = blockIdx.x * 256 + threadIdx.x;
  const float v = P[i];
  const unsigned short h = f2bf(v);
  PHI[i] = h;
  PLO[i] = f2bf(v - bf2f(h));
}

// ---------------------------------------------------------------------------
// x fp32 -> bf16 (for glds GEMM path)
// ---------------------------------------------------------------------------
__global__ __launch_bounds__(256) void xconv(const float* __restrict__ x,
                                             ushort_t* __restrict__ xb)
{
  const size_t i = ((size_t)blockIdx.x * 256 + threadIdx.x) * 8;
  const float4 a = *(const float4*)&x[i];
  const float4 c = *(const float4*)&x[i + 4];
  short8 o;
  o[0] = f2bf(a.x); o[1] = f2bf(a.y); o[2] = f2bf(a.z); o[3] = f2bf(a.w);
  o[4] = f2bf(c.x); o[5] = f2bf(c.y); o[6] = f2bf(c.z); o[7] = f2bf(c.w);
  *(short8*)&xb[i] = o;
}

// ---------------------------------------------------------------------------
// bf16 MFMA GEMM: C[16384,1024] = A @ Bt^T. 128x128, BK=32.
// EPI: 0=C fp32, 1=C fp32+bias, 2=VT bf16 [bh][dh][n], 3=hi/lo bf16 split.
// ---------------------------------------------------------------------------
template<bool AF32, int EPI>
__global__ __launch_bounds__(256) void gemm_k(const float* __restrict__ Af,
                                              const ushort_t* __restrict__ Ab,
                                              const ushort_t* __restrict__ Bt,
                                              const float* __restrict__ bias,
                                              float* __restrict__ C,
                                              ushort_t* __restrict__ VT,
                                              ushort_t* __restrict__ OH,
                                              ushort_t* __restrict__ OL)
{
  constexpr int K = DM, N = DM;
  __shared__ ushort_t As[128 * 32];
  __shared__ ushort_t Bs[128 * 32];

  const int tid = threadIdx.x;
  const int l = tid & 63, w = tid >> 6;
  const int ll = l & 15, lh = l >> 4;
  const int wr = w >> 1, wc = w & 1;

  const int bid = blockIdx.x;
  const int swz = (bid & 7) * ((int)gridDim.x >> 3) + (bid >> 3);
  const int bm = swz >> 3, bn = swz & 7;
  const int row0 = bm * 128, col0 = bn * 128;

  const int pb0 = w * 128 + l, pb1 = pb0 + 64;
  const int brow0 = pb0 >> 2, bkq0 = (pb0 & 3) ^ ((brow0 >> 1) & 3);
  const int brow1 = pb1 >> 2, bkq1 = (pb1 & 3) ^ ((brow1 >> 1) & 3);
  const ushort_t* bsrc0 = Bt + (size_t)(col0 + brow0) * K + bkq0 * 8;
  const ushort_t* bsrc1 = Bt + (size_t)(col0 + brow1) * K + bkq1 * 8;
  ushort_t* bdst0 = &Bs[(size_t)(w * 128) * 8];
  ushort_t* bdst1 = &Bs[(size_t)(w * 128 + 64) * 8];

  const int pa0 = tid, pa1 = tid + 256;
  const int arow0 = pa0 >> 2, akq0 = (pa0 & 3) ^ ((arow0 >> 1) & 3);
  const int arow1 = pa1 >> 2, akq1 = (pa1 & 3) ^ ((arow1 >> 1) & 3);
  const float* afs0 = nullptr; const float* afs1 = nullptr;
  const ushort_t* abs0_ = nullptr; const ushort_t* abs1_ = nullptr;
  if constexpr (AF32) {
    afs0 = Af + (size_t)(row0 + arow0) * K + akq0 * 8;
    afs1 = Af + (size_t)(row0 + arow1) * K + akq1 * 8;
  } else {
    abs0_ = Ab + (size_t)(row0 + brow0) * K + bkq0 * 8;
    abs1_ = Ab + (size_t)(row0 + brow1) * K + bkq1 * 8;
  }

  int aoff[4], boff[4];
  #pragma unroll
  for (int mt = 0; mt < 4; ++mt) {
    const int r = wr * 64 + mt * 16 + ll;
    aoff[mt] = (r * 4 + (lh ^ ((r >> 1) & 3))) * 8;
  }
  #pragma unroll
  for (int nt = 0; nt < 4; ++nt) {
    const int r = wc * 64 + nt * 16 + ll;
    boff[nt] = (r * 4 + (lh ^ ((r >> 1) & 3))) * 8;
  }

  f32x4 acc[4][4];
  #pragma unroll
  for (int i = 0; i < 4; ++i)
    #pragma unroll
    for (int j = 0; j < 4; ++j) acc[i][j] = (f32x4){0.f, 0.f, 0.f, 0.f};

  for (int k0 = 0; k0 < K; k0 += 32) {
    __syncthreads();
    if constexpr (AF32) {
      const float4 u0 = *(const float4*)(afs0 + k0);
      const float4 u1 = *(const float4*)(afs0 + k0 + 4);
      const float4 v0 = *(const float4*)(afs1 + k0);
      const float4 v1 = *(const float4*)(afs1 + k0 + 4);
      short8 s0, s1;
      s0[0] = f2bf(u0.x); s0[1] = f2bf(u0.y); s0[2] = f2bf(u0.z); s0[3] = f2bf(u0.w);
      s0[4] = f2bf(u1.x); s0[5] = f2bf(u1.y); s0[6] = f2bf(u1.z); s0[7] = f2bf(u1.w);
      s1[0] = f2bf(v0.x); s1[1] = f2bf(v0.y); s1[2] = f2bf(v0.z); s1[3] = f2bf(v0.w);
      s1[4] = f2bf(v1.x); s1[5] = f2bf(v1.y); s1[6] = f2bf(v1.z); s1[7] = f2bf(v1.w);
      *(short8*)&As[(size_t)pa0 * 8] = s0;
      *(short8*)&As[(size_t)pa1 * 8] = s1;
    } else {
      glds16(abs0_ + k0, &As[(size_t)(w * 128) * 8]);
      glds16(abs1_ + k0, &As[(size_t)(w * 128 + 64) * 8]);
    }
    glds16(bsrc0 + k0, bdst0);
    glds16(bsrc1 + k0, bdst1);
    __syncthreads();

    short8 av[4], bv[4];
    #pragma unroll
    for (int mt = 0; mt < 4; ++mt) av[mt] = *(const short8*)&As[aoff[mt]];
    #pragma unroll
    for (int nt = 0; nt < 4; ++nt) bv[nt] = *(const short8*)&Bs[boff[nt]];
    #pragma unroll
    for (int mt = 0; mt < 4; ++mt)
      #pragma unroll
      for (int nt = 0; nt < 4; ++nt)
        acc[mt][nt] = mfma16(av[mt], bv[nt], acc[mt][nt]);
  }

  if constexpr (EPI <= 1) {
    #pragma unroll
    for (int mt = 0; mt < 4; ++mt) {
      #pragma unroll
      for (int nt = 0; nt < 4; ++nt) {
        const int row = row0 + wr * 64 + mt * 16 + lh * 4;
        const int col = col0 + wc * 64 + nt * 16 + ll;
        const float bv_ = (EPI == 1) ? bias[col] : 0.f;
        #pragma unroll
        for (int j = 0; j < 4; ++j)
          C[(size_t)(row + j) * N + col] = acc[mt][nt][j] + bv_;
      }
    }
  } else if constexpr (EPI == 2) {
    #pragma unroll
    for (int mt = 0; mt < 4; ++mt) {
      #pragma unroll
      for (int nt = 0; nt < 4; ++nt) {
        const int rg = row0 + wr * 64 + mt * 16 + lh * 4;
        const int cg = col0 + wc * 64 + nt * 16 + ll;
        const int b = rg >> 12, n = rg & 4095;
        const int h = cg >> 6, dh = cg & 63;
        ushort4 o;
        o.x = f2bf(acc[mt][nt][0]); o.y = f2bf(acc[mt][nt][1]);
        o.z = f2bf(acc[mt][nt][2]); o.w = f2bf(acc[mt][nt][3]);
        *(ushort4*)&VT[(((size_t)b * 16 + h) * 64 + dh) * 4096 + n] = o;
      }
    }
  } else {   // EPI == 3: hi/lo split bf16, row-major
    #pragma unroll
    for (int mt = 0; mt < 4; ++mt) {
      #pragma unroll
      for (int nt = 0; nt < 4; ++nt) {
        const int row = row0 + wr * 64 + mt * 16 + lh * 4;
        const int col = col0 + wc * 64 + nt * 16 + ll;
        #pragma unroll
        for (int j = 0; j < 4; ++j) {
          const float v = acc[mt][nt][j];
          const unsigned short hh = f2bf(v);
          OH[(size_t)(row + j) * N + col] = hh;
          OL[(size_t)(row + j) * N + col] = f2bf(v - bf2f(hh));
        }
      }
    }
  }
}

// ---------------------------------------------------------------------------
// kmax3: global max of dn*(K.P^T), split-MFMA, P-frags in registers.
// grid 1024 = 64 bh x 16 chunks (256 rows). 256 thr (4 waves = 4 m-groups).
// ---------------------------------------------------------------------------
__global__ __launch_bounds__(256) void kmax3(const ushort_t* __restrict__ KHI,
                                             const ushort_t* __restrict__ KLO,
                                             const ushort_t* __restrict__ PHI,
                                             const ushort_t* __restrict__ PLO,
                                             unsigned* __restrict__ mxp)
{
  const int tid = threadIdx.x;
  const int l = tid & 63, mg = tid >> 6;
  const int ll = l & 15, lh = l >> 4;
  const int bh = blockIdx.x >> 4, ck = blockIdx.x & 15;
  const int b = bh >> 4, h = bh & 15;

  short8 pfh[4][2], pfl[4][2];
  #pragma unroll
  for (int mt = 0; mt < 4; ++mt)
    #pragma unroll
    for (int ks = 0; ks < 2; ++ks) {
      const size_t off = (size_t)(mg * 64 + mt * 16 + ll) * 64 + ks * 32 + lh * 8;
      pfh[mt][ks] = *(const short8*)&PHI[off];
      pfl[mt][ks] = *(const short8*)&PLO[off];
    }

  float vmax = -3.0e38f;
  for (int it = 0; it < 16; ++it) {
    const int nb = ck * 256 + it * 16;
    const size_t off = ((size_t)(b * NSEQ + nb + ll)) * DM + h * DHD + lh * 8;
    short8 kh0 = *(const short8*)&KHI[off];
    short8 kh1 = *(const short8*)&KHI[off + 32];
    short8 kl0 = *(const short8*)&KLO[off];
    short8 kl1 = *(const short8*)&KLO[off + 32];
    #pragma unroll
    for (int mt = 0; mt < 4; ++mt) {
      f32x4 acc = (f32x4){0.f, 0.f, 0.f, 0.f};
      acc = mfma16(kh0, pfh[mt][0], acc); acc = mfma16(kh1, pfh[mt][1], acc);
      acc = mfma16(kh0, pfl[mt][0], acc); acc = mfma16(kh1, pfl[mt][1], acc);
      acc = mfma16(kl0, pfh[mt][0], acc); acc = mfma16(kl1, pfh[mt][1], acc);
      vmax = fmaxf(vmax, fmaxf(fmaxf(acc[0], acc[1]), fmaxf(acc[2], acc[3])));
    }
  }
  vmax *= DN;
  #pragma unroll
  for (int off = 1; off < 64; off <<= 1) vmax = fmaxf(vmax, __shfl_xor(vmax, off, 64));
  if (l == 0) atomicMax(mxp, __float_as_uint(vmax));
}

// ---------------------------------------------------------------------------
// kside4: split-MFMA dd -> kp -> 16x16x16 PV (register handoff, no LDS).
// grid 1024 = 64 bh x 16 chunks (256 rows). 256 thr (4 waves = 4 m-groups).
// ---------------------------------------------------------------------------
__global__ __launch_bounds__(256) void kside4(const ushort_t* __restrict__ KHI,
                                              const ushort_t* __restrict__ KLO,
                                              const ushort_t* __restrict__ VT,
                                              const ushort_t* __restrict__ PHI,
                                              const ushort_t* __restrict__ PLO,
                                              const unsigned* __restrict__ mxp,
                                              float* __restrict__ ctx,
                                              float* __restrict__ kcs)
{
  const int tid = threadIdx.x;
  const int l = tid & 63, mg = tid >> 6;
  const int ll = l & 15, lh = l >> 4;
  const int bh = blockIdx.x >> 4, ck = blockIdx.x & 15;
  const int b = bh >> 4, h = bh & 15;

  short8 pfh[4][2], pfl[4][2];
  #pragma unroll
  for (int mt = 0; mt < 4; ++mt)
    #pragma unroll
    for (int ks = 0; ks < 2; ++ks) {
      const size_t off = (size_t)(mg * 64 + mt * 16 + ll) * 64 + ks * 32 + lh * 8;
      pfh[mt][ks] = *(const short8*)&PHI[off];
      pfl[mt][ks] = *(const short8*)&PLO[off];
    }
  const float mx = __uint_as_float(*mxp);

  f32x4 apv[4][4];
  #pragma unroll
  for (int i = 0; i < 4; ++i)
    #pragma unroll
    for (int j = 0; j < 4; ++j) apv[i][j] = (f32x4){0.f, 0.f, 0.f, 0.f};
  float kcp[4] = {0.f, 0.f, 0.f, 0.f};

  for (int it = 0; it < 16; ++it) {
    const int nb = ck * 256 + it * 16;
    const size_t off = ((size_t)(b * NSEQ + nb + ll)) * DM + h * DHD + lh * 8;
    short8 kh0 = *(const short8*)&KHI[off];
    short8 kh1 = *(const short8*)&KHI[off + 32];
    short8 kl0 = *(const short8*)&KLO[off];
    short8 kl1 = *(const short8*)&KLO[off + 32];

    float ssq = 0.f;
    #pragma unroll
    for (int e = 0; e < 8; ++e) {
      const float a0 = bf2f((ushort_t)kh0[e]) + bf2f((ushort_t)kl0[e]);
      const float a1 = bf2f((ushort_t)kh1[e]) + bf2f((ushort_t)kl1[e]);
      ssq += a0 * a0 + a1 * a1;
    }
    ssq += __shfl_xor(ssq, 16, 64);
    ssq += __shfl_xor(ssq, 32, 64);
    const float dgl = HALF_DN2 * ssq;          // diag of row nb+ll
    float dgv[4];
    #pragma unroll
    for (int jr = 0; jr < 4; ++jr)
      dgv[jr] = __shfl(dgl, ((l >> 4) << 2) + jr, 64);   // diag[n = lh*4+jr]

    short4v qa[4];
    #pragma unroll
    for (int mt = 0; mt < 4; ++mt) {
      f32x4 acc = (f32x4){0.f, 0.f, 0.f, 0.f};
      acc = mfma16(kh0, pfh[mt][0], acc); acc = mfma16(kh1, pfh[mt][1], acc);
      acc = mfma16(kh0, pfl[mt][0], acc); acc = mfma16(kh1, pfl[mt][1], acc);
      acc = mfma16(kl0, pfh[mt][0], acc); acc = mfma16(kl1, pfh[mt][1], acc);
      short4v o; float s = 0.f;
      #pragma unroll
      for (int jr = 0; jr < 4; ++jr) {
        const float kv = RATIO * (__expf(acc[jr] * DN - dgv[jr] - mx) + EPSF);
        const ushort_t ub = f2bf(kv);
        o[jr] = (short)ub;
        s += bf2f(ub);
      }
      qa[mt] = o;
      kcp[mt] += s;
    }
    #pragma unroll
    for (int dt = 0; dt < 4; ++dt) {
      const short4v vf = *(const short4v*)&VT[((size_t)bh * 64 + dt * 16 + ll) * NSEQ + nb + lh * 4];
      #pragma unroll
      for (int mt = 0; mt < 4; ++mt)
        apv[mt][dt] = mfma16x16(qa[mt], vf, apv[mt][dt]);
    }
  }

  #pragma unroll
  for (int mt = 0; mt < 4; ++mt) {
    float s = kcp[mt];
    s += __shfl_xor(s, 16, 64);
    s += __shfl_xor(s, 32, 64);
    if (lh == 0) atomicAdd(&kcs[bh * MF + mg * 64 + mt * 16 + ll], s);
  }
  #pragma unroll
  for (int mt = 0; mt < 4; ++mt)
    #pragma unroll
    for (int dt = 0; dt < 4; ++dt)
      #pragma unroll
      for (int jr = 0; jr < 4; ++jr) {
        const int m = mg * 64 + mt * 16 + lh * 4 + jr;     // C row = A-side = m
        const int dh = dt * 16 + ll;                        // C col = B-side = dh
        atomicAdd(&ctx[((size_t)bh * MF + m) * DHD + dh], apv[mt][dt][jr]);
      }
}

// ---------------------------------------------------------------------------
// ctx fp32 [bh][m][dh] -> CTH/CTL bf16 [bh][dh][m].
// ---------------------------------------------------------------------------
__global__ __launch_bounds__(256) void ctx2bf(const float* __restrict__ ctx,
                                              ushort_t* __restrict__ CTH,
                                              ushort_t* __restrict__ CTL)
{
  __shared__ float ts[64][68];
  const int tid = threadIdx.x;
  const int bh = blockIdx.x >> 2, mc = blockIdx.x & 3;
  const int r = tid >> 4, c4 = (tid & 15) * 4;
  #pragma unroll
  for (int i = 0; i < 4; ++i) {
    const int m = mc * 64 + r + i * 16;
    *(float4*)&ts[r + i * 16][c4] = *(const float4*)&ctx[((size_t)bh * MF + m) * DHD + c4];
  }
  __syncthreads();
  #pragma unroll
  for (int i = 0; i < 4; ++i) {
    const int dh = r + i * 16;
    ushort4 oh, ol;
    #pragma unroll
    for (int k = 0; k < 4; ++k) {
      const float v = ts[c4 + k][dh];
      const unsigned short hh = f2bf(v);
      ((unsigned short*)&oh)[k] = hh;
      ((unsigned short*)&ol)[k] = f2bf(v - bf2f(hh));
    }
    const size_t o = ((size_t)bh * 64 + dh) * MF + mc * 64 + c4;
    *(ushort4*)&CTH[o] = oh;
    *(ushort4*)&CTL[o] = ol;
  }
}

// ---------------------------------------------------------------------------
// qside5: transposed dd (A=P,B=Q) -> per-lane softmax -> 16x16x16 PV with
// register qp handoff. P/CT/kcs staged once per block in frag-contiguous LDS.
// grid 1024 = 64 bh x 16 tiles (256 rows). 512 thr (8 waves x 2 row-tiles).
// ---------------------------------------------------------------------------
__global__ __launch_bounds__(512, 2) void qside5(const ushort_t* __restrict__ QHI,
                                                 const ushort_t* __restrict__ QLO,
                                                 const ushort_t* __restrict__ PHI,
                                                 const ushort_t* __restrict__ PLO,
                                                 const float* __restrict__ kcs,
                                                 const ushort_t* __restrict__ CTH,
                                                 const ushort_t* __restrict__ CTL,
                                                 ushort_t* __restrict__ attb)
{
  extern __shared__ ushort_t lds[];
  ushort_t* pst = lds;            // [((mt*2+ks)*2+p)*64+l]*8  : 32768 ushorts
  ushort_t* ctf = lds + 32768;    // [((p*16+mt)*4+dt)*64+l]*4 : 32768 ushorts
  ushort_t* kcf = lds + 65536;    // [(mt*64+l)]*4             : 4096  ushorts

  const int tid = threadIdx.x;
  const int l = tid & 63, w = tid >> 6;
  const int ll = l & 15, lh = l >> 4;
  const int bh = blockIdx.x >> 4, qt = blockIdx.x & 15;
  const int b = bh >> 4, h = bh & 15;

  // ---- stage P fragments ----
  #pragma unroll
  for (int i = 0; i < 8; ++i) {
    const int f = tid + i * 512;
    const int fl = f & 63, r = f >> 6;
    const int p = r & 1, ks = (r >> 1) & 1, mt = r >> 2;
    const ushort_t* src = (p ? PLO : PHI) + (mt * 16 + (fl & 15)) * 64 + ks * 32 + (fl >> 4) * 8;
    *(short8*)&pst[f * 8] = *(const short8*)src;
  }
  // ---- stage ct fragments ----
  #pragma unroll
  for (int i = 0; i < 16; ++i) {
    const int g = tid + i * 512;
    const int gl = g & 63, r = g >> 6;
    const int dt = r & 3, r2 = r >> 2, mt = r2 & 15, p = r2 >> 4;
    const ushort_t* src = (p ? CTL : CTH) +
        ((size_t)bh * 64 + dt * 16 + (gl & 15)) * MF + mt * 16 + (gl >> 4) * 4;
    *(ushort4*)&ctf[g * 4] = *(const ushort4*)src;
  }
  // ---- stage kcs fragments (col0=hi, col1=lo, cols>=2 zero) ----
  #pragma unroll
  for (int i = 0; i < 2; ++i) {
    const int u = tid + i * 512;
    const int ul = u & 63, mt = u >> 6;
    const int cll = ul & 15, clh = ul >> 4;
    ushort4 o = make_ushort4(0, 0, 0, 0);
    if (cll < 2) {
      #pragma unroll
      for (int e = 0; e < 4; ++e) {
        const float kv = kcs[bh * MF + mt * 16 + clh * 4 + e];
        const unsigned short hi = f2bf(kv);
        ((ushort_t*)&o)[e] = (cll == 0) ? hi : f2bf(kv - bf2f(hi));
      }
    }
    *(ushort4*)&kcf[u * 4] = o;
  }
  __syncthreads();

  const int rowb0 = b * NSEQ + qt * 256 + w * 32;   // tile0 rows; tile1 = +16

  // ---- Q fragments (lane ll = q-row) ----
  short8 qh0[2], ql0[2], qh1[2], ql1[2];
  #pragma unroll
  for (int ks = 0; ks < 2; ++ks) {
    const size_t off = (size_t)(rowb0 + ll) * DM + h * DHD + ks * 32 + lh * 8;
    qh0[ks] = *(const short8*)&QHI[off];
    ql0[ks] = *(const short8*)&QLO[off];
    qh1[ks] = *(const short8*)&QHI[off + (size_t)16 * DM];
    ql1[ks] = *(const short8*)&QLO[off + (size_t)16 * DM];
  }
  float ssq0 = 0.f, ssq1 = 0.f;
  #pragma unroll
  for (int ks = 0; ks < 2; ++ks)
    #pragma unroll
    for (int e = 0; e < 8; ++e) {
      const float a0 = bf2f((ushort_t)qh0[ks][e]) + bf2f((ushort_t)ql0[ks][e]);
      const float a1 = bf2f((ushort_t)qh1[ks][e]) + bf2f((ushort_t)ql1[ks][e]);
      ssq0 += a0 * a0; ssq1 += a1 * a1;
    }
  ssq0 += __shfl_xor(ssq0, 16, 64); ssq0 += __shfl_xor(ssq0, 32, 64);
  ssq1 += __shfl_xor(ssq1, 16, 64); ssq1 += __shfl_xor(ssq1, 32, 64);
  const float dg0 = HALF_DN2 * ssq0, dg1 = HALF_DN2 * ssq1;

  // ---- dd (lane ll = n, regs = m) ----
  f32x4 dd0[16], dd1[16];
  #pragma unroll
  for (int mt = 0; mt < 16; ++mt) {
    const short8 ph0 = *(const short8*)&pst[((mt * 2 + 0) * 2 + 0) * 512 + l * 8];
    const short8 ph1 = *(const short8*)&pst[((mt * 2 + 1) * 2 + 0) * 512 + l * 8];
    const short8 pl0 = *(const short8*)&pst[((mt * 2 + 0) * 2 + 1) * 512 + l * 8];
    const short8 pl1 = *(const short8*)&pst[((mt * 2 + 1) * 2 + 1) * 512 + l * 8];
    f32x4 a0 = (f32x4){0.f, 0.f, 0.f, 0.f};
    f32x4 a1 = (f32x4){0.f, 0.f, 0.f, 0.f};
    a0 = mfma16(ph0, qh0[0], a0); a0 = mfma16(ph1, qh0[1], a0);
    a0 = mfma16(ph0, ql0[0], a0); a0 = mfma16(ph1, ql0[1], a0);
    a0 = mfma16(pl0, qh0[0], a0); a0 = mfma16(pl1, qh0[1], a0);
    a1 = mfma16(ph0, qh1[0], a1); a1 = mfma16(ph1, qh1[1], a1);
    a1 = mfma16(ph0, ql1[0], a1); a1 = mfma16(ph1, ql1[1], a1);
    a1 = mfma16(pl0, qh1[0], a1); a1 = mfma16(pl1, qh1[1], a1);
    dd0[mt] = a0; dd1[mt] = a1;
  }

  // ---- per-row (per-lane) max ----
  float rm0 = -3.0e38f, rm1 = -3.0e38f;
  #pragma unroll
  for (int mt = 0; mt < 16; ++mt) {
    rm0 = fmaxf(rm0, fmaxf(fmaxf(dd0[mt][0], dd0[mt][1]), fmaxf(dd0[mt][2], dd0[mt][3])));
    rm1 = fmaxf(rm1, fmaxf(fmaxf(dd1[mt][0], dd1[mt][1]), fmaxf(dd1[mt][2], dd1[mt][3])));
  }
  rm0 = fmaxf(rm0, __shfl_xor(rm0, 16, 64)); rm0 = fmaxf(rm0, __shfl_xor(rm0, 32, 64));
  rm1 = fmaxf(rm1, __shfl_xor(rm1, 16, 64)); rm1 = fmaxf(rm1, __shfl_xor(rm1, 32, 64));
  rm0 *= DN; rm1 *= DN;

  // ---- qp (bf16-rounded), packed directly as 16x16x16 A-fragments ----
  short4v qp0[16], qp1[16];
  #pragma unroll
  for (int mt = 0; mt < 16; ++mt) {
    short4v o0, o1;
    #pragma unroll
    for (int jr = 0; jr < 4; ++jr) {
      o0[jr] = (short)f2bf(RATIO * (__expf(dd0[mt][jr] * DN - dg0 - rm0) + EPSF));
      o1[jr] = (short)f2bf(RATIO * (__expf(dd1[mt][jr] * DN - dg1 - rm1) + EPSF));
    }
    qp0[mt] = o0; qp1[mt] = o1;
  }

  // ---- PV + denominator fold ----
  f32x4 av0[4], av1[4];
  #pragma unroll
  for (int dt = 0; dt < 4; ++dt) {
    av0[dt] = (f32x4){0.f, 0.f, 0.f, 0.f};
    av1[dt] = (f32x4){0.f, 0.f, 0.f, 0.f};
  }
  f32x4 aK0 = (f32x4){0.f, 0.f, 0.f, 0.f};
  f32x4 aK1 = (f32x4){0.f, 0.f, 0.f, 0.f};
  #pragma unroll
  for (int mt = 0; mt < 16; ++mt) {
    const short4v kcv = *(const short4v*)&kcf[mt * 256 + l * 4];
    aK0 = mfma16x16(qp0[mt], kcv, aK0);
    aK1 = mfma16x16(qp1[mt], kcv, aK1);
    #pragma unroll
    for (int dt = 0; dt < 4; ++dt) {
      const short4v ch = *(const short4v*)&ctf[((0 * 16 + mt) * 4 + dt) * 256 + l * 4];
      const short4v cl = *(const short4v*)&ctf[((16 + mt) * 4 + dt) * 256 + l * 4];
      av0[dt] = mfma16x16(qp0[mt], ch, av0[dt]);
      av0[dt] = mfma16x16(qp0[mt], cl, av0[dt]);
      av1[dt] = mfma16x16(qp1[mt], ch, av1[dt]);
      av1[dt] = mfma16x16(qp1[mt], cl, av1[dt]);
    }
  }

  // ---- 1/den (den parts live at lanes ll=0,1 of each lh group) ----
  float di0[4], di1[4];
  #pragma unroll
  for (int jr = 0; jr < 4; ++jr) {
    const float h0 = __shfl(aK0[jr], (l & 48), 64);
    const float l0 = __shfl(aK0[jr], (l & 48) | 1, 64);
    const float h1 = __shfl(aK1[jr], (l & 48), 64);
    const float l1 = __shfl(aK1[jr], (l & 48) | 1, 64);
    di0[jr] = 1.0f / (h0 + l0);
    di1[jr] = 1.0f / (h1 + l1);
  }

  // ---- write ATT bf16 (C layout: row = n = lh*4+jr, col = dh = dt*16+ll) ----
  #pragma unroll
  for (int dt = 0; dt < 4; ++dt)
    #pragma unroll
    for (int jr = 0; jr < 4; ++jr) {
      const int col = h * DHD + dt * 16 + ll;
      attb[(size_t)(rowb0 + lh * 4 + jr) * DM + col] = f2bf(av0[dt][jr] * di0[jr]);
      attb[(size_t)(rowb0 + 16 + lh * 4 + jr) * DM + col] = f2bf(av1[dt][jr] * di1[jr]);
    }
}

// ---------------------------------------------------------------------------
extern "C" void kernel_launch(void* const* d_in, const int* in_sizes, int n_in,
                              void* d_out, int out_size, void* d_ws, size_t ws_size,
                              hipStream_t stream)
{
  const float* x  = (const float*)d_in[0];
  const float* Wq = (const float*)d_in[1];
  const float* Wk = (const float*)d_in[2];
  const float* Wv = (const float*)d_in[3];
  const float* Wo = (const float*)d_in[4];
  const float* bo = (const float*)d_in[5];
  const float* P  = (const float*)d_in[6];
  float* out = (float*)d_out;

  char* wp = (char*)d_ws;
  ushort_t* QHI = (ushort_t*)(wp + 0);
  ushort_t* QLO = (ushort_t*)(wp + 33554432);
  ushort_t* KHI = (ushort_t*)(wp + 67108864);    // ATTB overlays later
  ushort_t* KLO = (ushort_t*)(wp + 100663296);
  ushort_t* VT  = (ushort_t*)(wp + 134217728);
  ushort_t* Wqt = (ushort_t*)(wp + 167772160);
  ushort_t* Wkt = (ushort_t*)(wp + 169869312);
  ushort_t* Wvt = (ushort_t*)(wp + 171966464);
  ushort_t* Wot = (ushort_t*)(wp + 174063616);
  ushort_t* PHI = (ushort_t*)(wp + 176160768);
  ushort_t* PLO = (ushort_t*)(wp + 176193536);
  float*    CTX = (float*)(wp + 176226304);      // 4 MiB
  float*    KCS = (float*)(wp + 180420608);      // 64 KiB
  unsigned* MX  = (unsigned*)(wp + 180486144);   // 256 B
  ushort_t* CTH = (ushort_t*)(wp + 180486400);
  ushort_t* CTL = (ushort_t*)(wp + 182583552);
  ushort_t* XB  = (ushort_t*)(wp + 184680704);   // optional, 32 MiB
  ushort_t* ATTB = KHI;

  const bool useXB = ws_size >= 218235136ull;

  dim3 tg(16, 16);
  wtrans<<<tg, 256, 0, stream>>>(Wq, Wqt);
  wtrans<<<tg, 256, 0, stream>>>(Wk, Wkt);
  wtrans<<<tg, 256, 0, stream>>>(Wv, Wvt);
  wtrans<<<tg, 256, 0, stream>>>(Wo, Wot);
  psplit<<<64, 256, 0, stream>>>(P, PHI, PLO);

  if (useXB) {
    xconv<<<8192, 256, 0, stream>>>(x, XB);
    gemm_k<false, 3><<<1024, 256, 0, stream>>>(nullptr, XB, Wqt, nullptr, nullptr, nullptr, QHI, QLO);
    gemm_k<false, 3><<<1024, 256, 0, stream>>>(nullptr, XB, Wkt, nullptr, nullptr, nullptr, KHI, KLO);
    gemm_k<false, 2><<<1024, 256, 0, stream>>>(nullptr, XB, Wvt, nullptr, nullptr, VT, nullptr, nullptr);
  } else {
    gemm_k<true, 3><<<1024, 256, 0, stream>>>(x, nullptr, Wqt, nullptr, nullptr, nullptr, QHI, QLO);
    gemm_k<true, 3><<<1024, 256, 0, stream>>>(x, nullptr, Wkt, nullptr, nullptr, nullptr, KHI, KLO);
    gemm_k<true, 2><<<1024, 256, 0, stream>>>(x, nullptr, Wvt, nullptr, nullptr, VT, nullptr, nullptr);
  }

  hipMemsetAsync(CTX, 0, 4194304 + 65536 + 256, stream);   // CTX + KCS + MX

  kmax3<<<1024, 256, 0, stream>>>(KHI, KLO, PHI, PLO, MX);
  kside4<<<1024, 256, 0, stream>>>(KHI, KLO, VT, PHI, PLO, MX, CTX, KCS);
  ctx2bf<<<256, 256, 0, stream>>>(CTX, CTH, CTL);
  qside5<<<1024, 512, 139264, stream>>>(QHI, QLO, PHI, PLO, KCS, CTH, CTL, ATTB);

  gemm_k<false, 1><<<1024, 256, 0, stream>>>(nullptr, ATTB, Wot, bo, out, nullptr, nullptr, nullptr);
}

// Round 5
// 427.595 us; speedup vs baseline: 9.0375x; 1.2499x over previous
//
#include <hip/hip_runtime.h>
#include <math.h>

#define NB 4
#define NSEQ 4096
#define DM 1024
#define NHEAD 16
#define DHD 64
#define MF 256
#define ROWS 16384

#define DN 0.35355339059327373f
#define RATIO 0.0625f
#define HALF_DN2 0.0625f
#define EPSF 1.0e-4f
#define THR_DEFER 4.0f

typedef __attribute__((ext_vector_type(4))) float f32x4;
typedef __attribute__((ext_vector_type(8))) short short8;
typedef __attribute__((ext_vector_type(4))) short short4v;
typedef __attribute__((ext_vector_type(8))) __bf16 bf16x8;
typedef unsigned short ushort_t;

__device__ __forceinline__ unsigned short f2bf(float f) {
  unsigned int u = __builtin_bit_cast(unsigned int, f);
  u += 0x7FFFu + ((u >> 16) & 1u);
  return (unsigned short)(u >> 16);
}
__device__ __forceinline__ float bf2f(unsigned short h) {
  unsigned int u = ((unsigned int)h) << 16;
  return __builtin_bit_cast(float, u);
}

__device__ __forceinline__ f32x4 mfma16(short8 a, short8 b, f32x4 c) {
  return __builtin_amdgcn_mfma_f32_16x16x32_bf16(
      __builtin_bit_cast(bf16x8, a), __builtin_bit_cast(bf16x8, b), c, 0, 0, 0);
}

// 16x16x16 bf16 MFMA (K=16). Fragment mappings validated end-to-end in r4.
__device__ __forceinline__ f32x4 mfma16x16(short4v a, short4v b, f32x4 c) {
#if __has_builtin(__builtin_amdgcn_mfma_f32_16x16x16bf16_1k)
  return __builtin_amdgcn_mfma_f32_16x16x16bf16_1k(a, b, c, 0, 0, 0);
#elif __has_builtin(__builtin_amdgcn_mfma_f32_16x16x16_bf16)
  typedef __attribute__((ext_vector_type(4))) __bf16 bf16x4;
  return __builtin_amdgcn_mfma_f32_16x16x16_bf16(
      __builtin_bit_cast(bf16x4, a), __builtin_bit_cast(bf16x4, b), c, 0, 0, 0);
#else
  asm volatile("s_nop 1\n\t"
               "v_mfma_f32_16x16x16_bf16 %0, %1, %2, %0\n\t"
               "s_nop 7"
               : "+v"(c) : "v"(a), "v"(b));
  return c;
#endif
}

__device__ __forceinline__ void glds16(const void* g, void* l) {
  __builtin_amdgcn_global_load_lds(
      (const __attribute__((address_space(1))) unsigned int*)g,
      (__attribute__((address_space(3))) unsigned int*)l, 16, 0, 0);
}

// ---------------------------------------------------------------------------
// Weight transpose-cast: Wt[n][k] = bf16(W[k][n]).
// ---------------------------------------------------------------------------
__global__ __launch_bounds__(256) void wtrans(const float* __restrict__ W,
                                              ushort_t* __restrict__ Wt)
{
  __shared__ float ts[64][68];
  const int tid = threadIdx.x;
  const int k0 = blockIdx.y * 64, n0 = blockIdx.x * 64;
  const int r = tid >> 4, c4 = (tid & 15) * 4;
  #pragma unroll
  for (int i = 0; i < 4; ++i) {
    float4 v = *(const float4*)&W[(size_t)(k0 + r + i * 16) * DM + n0 + c4];
    *(float4*)&ts[r + i * 16][c4] = v;
  }
  __syncthreads();
  #pragma unroll
  for (int i = 0; i < 4; ++i) {
    const int n = r + i * 16;
    ushort4 o;
    o.x = f2bf(ts[c4 + 0][n]); o.y = f2bf(ts[c4 + 1][n]);
    o.z = f2bf(ts[c4 + 2][n]); o.w = f2bf(ts[c4 + 3][n]);
    *(ushort4*)&Wt[(size_t)(n0 + n) * DM + k0 + c4] = o;
  }
}

// ---------------------------------------------------------------------------
// P split: PHI/PLO bf16 [256][64]
// ---------------------------------------------------------------------------
__global__ __launch_bounds__(256) void psplit(const float* __restrict__ P,
                                              ushort_t* __restrict__ PHI,
                                              ushort_t* __restrict__ PLO)
{
  const int i = blockIdx.x * 256 + threadIdx.x;
  const float v = P[i];
  const unsigned short h = f2bf(v);
  PHI[i] = h;
  PLO[i] = f2bf(v - bf2f(h));
}

// ---------------------------------------------------------------------------
// x fp32 -> bf16
// ---------------------------------------------------------------------------
__global__ __launch_bounds__(256) void xconv(const float* __restrict__ x,
                                             ushort_t* __restrict__ xb)
{
  const size_t i = ((size_t)blockIdx.x * 256 + threadIdx.x) * 8;
  const float4 a = *(const float4*)&x[i];
  const float4 c = *(const float4*)&x[i + 4];
  short8 o;
  o[0] = f2bf(a.x); o[1] = f2bf(a.y); o[2] = f2bf(a.z); o[3] = f2bf(a.w);
  o[4] = f2bf(c.x); o[5] = f2bf(c.y); o[6] = f2bf(c.z); o[7] = f2bf(c.w);
  *(short8*)&xb[i] = o;
}

// ---------------------------------------------------------------------------
// bf16 MFMA GEMM: C[16384,1024] = A @ Bt^T. 128x128, BK=32.
// EPI: 1=C fp32+bias, 2=VT bf16 [bh][dh][n],
//      3=hi|lo interleaved per (row,head) [row][h][128] + diag [bh][n].
// ---------------------------------------------------------------------------
template<int EPI>
__global__ __launch_bounds__(256) void gemm_k(const ushort_t* __restrict__ Ab,
                                              const ushort_t* __restrict__ Bt,
                                              const float* __restrict__ bias,
                                              float* __restrict__ C,
                                              ushort_t* __restrict__ VT,
                                              ushort_t* __restrict__ OHL,
                                              float* __restrict__ DIAG)
{
  constexpr int K = DM, N = DM;
  __shared__ ushort_t As[128 * 32];
  __shared__ ushort_t Bs[128 * 32];

  const int tid = threadIdx.x;
  const int l = tid & 63, w = tid >> 6;
  const int ll = l & 15, lh = l >> 4;
  const int wr = w >> 1, wc = w & 1;

  const int bid = blockIdx.x;
  const int swz = (bid & 7) * ((int)gridDim.x >> 3) + (bid >> 3);
  const int bm = swz >> 3, bn = swz & 7;
  const int row0 = bm * 128, col0 = bn * 128;

  const int pb0 = w * 128 + l, pb1 = pb0 + 64;
  const int brow0 = pb0 >> 2, bkq0 = (pb0 & 3) ^ ((brow0 >> 1) & 3);
  const int brow1 = pb1 >> 2, bkq1 = (pb1 & 3) ^ ((brow1 >> 1) & 3);
  const ushort_t* bsrc0 = Bt + (size_t)(col0 + brow0) * K + bkq0 * 8;
  const ushort_t* bsrc1 = Bt + (size_t)(col0 + brow1) * K + bkq1 * 8;
  ushort_t* bdst0 = &Bs[(size_t)(w * 128) * 8];
  ushort_t* bdst1 = &Bs[(size_t)(w * 128 + 64) * 8];

  const ushort_t* asrc0 = Ab + (size_t)(row0 + brow0) * K + bkq0 * 8;
  const ushort_t* asrc1 = Ab + (size_t)(row0 + brow1) * K + bkq1 * 8;

  int aoff[4], boff[4];
  #pragma unroll
  for (int mt = 0; mt < 4; ++mt) {
    const int r = wr * 64 + mt * 16 + ll;
    aoff[mt] = (r * 4 + (lh ^ ((r >> 1) & 3))) * 8;
  }
  #pragma unroll
  for (int nt = 0; nt < 4; ++nt) {
    const int r = wc * 64 + nt * 16 + ll;
    boff[nt] = (r * 4 + (lh ^ ((r >> 1) & 3))) * 8;
  }

  f32x4 acc[4][4];
  #pragma unroll
  for (int i = 0; i < 4; ++i)
    #pragma unroll
    for (int j = 0; j < 4; ++j) acc[i][j] = (f32x4){0.f, 0.f, 0.f, 0.f};

  for (int k0 = 0; k0 < K; k0 += 32) {
    __syncthreads();
    glds16(asrc0 + k0, &As[(size_t)(w * 128) * 8]);
    glds16(asrc1 + k0, &As[(size_t)(w * 128 + 64) * 8]);
    glds16(bsrc0 + k0, bdst0);
    glds16(bsrc1 + k0, bdst1);
    __syncthreads();

    short8 av[4], bv[4];
    #pragma unroll
    for (int mt = 0; mt < 4; ++mt) av[mt] = *(const short8*)&As[aoff[mt]];
    #pragma unroll
    for (int nt = 0; nt < 4; ++nt) bv[nt] = *(const short8*)&Bs[boff[nt]];
    #pragma unroll
    for (int mt = 0; mt < 4; ++mt)
      #pragma unroll
      for (int nt = 0; nt < 4; ++nt)
        acc[mt][nt] = mfma16(av[mt], bv[nt], acc[mt][nt]);
  }

  if constexpr (EPI == 1) {
    #pragma unroll
    for (int mt = 0; mt < 4; ++mt) {
      #pragma unroll
      for (int nt = 0; nt < 4; ++nt) {
        const int row = row0 + wr * 64 + mt * 16 + lh * 4;
        const int col = col0 + wc * 64 + nt * 16 + ll;
        const float bv_ = bias[col];
        #pragma unroll
        for (int j = 0; j < 4; ++j)
          C[(size_t)(row + j) * N + col] = acc[mt][nt][j] + bv_;
      }
    }
  } else if constexpr (EPI == 2) {
    #pragma unroll
    for (int mt = 0; mt < 4; ++mt) {
      #pragma unroll
      for (int nt = 0; nt < 4; ++nt) {
        const int rg = row0 + wr * 64 + mt * 16 + lh * 4;
        const int cg = col0 + wc * 64 + nt * 16 + ll;
        const int b = rg >> 12, n = rg & 4095;
        const int h = cg >> 6, dh = cg & 63;
        ushort4 o;
        o.x = f2bf(acc[mt][nt][0]); o.y = f2bf(acc[mt][nt][1]);
        o.z = f2bf(acc[mt][nt][2]); o.w = f2bf(acc[mt][nt][3]);
        *(ushort4*)&VT[(((size_t)b * 16 + h) * 64 + dh) * 4096 + n] = o;
      }
    }
  } else {   // EPI == 3
    const int hglob = (col0 >> 6) + wc;
    #pragma unroll
    for (int mt = 0; mt < 4; ++mt) {
      float rssq[4] = {0.f, 0.f, 0.f, 0.f};
      #pragma unroll
      for (int nt = 0; nt < 4; ++nt) {
        const int row = row0 + wr * 64 + mt * 16 + lh * 4;
        const int e = nt * 16 + ll;
        #pragma unroll
        for (int j = 0; j < 4; ++j) {
          const float v = acc[mt][nt][j];
          rssq[j] += v * v;
          const unsigned short hh = f2bf(v);
          const size_t base = ((size_t)(row + j) * 16 + hglob) * 128 + e;
          OHL[base] = hh;
          OHL[base + 64] = f2bf(v - bf2f(hh));
        }
      }
      #pragma unroll
      for (int j = 0; j < 4; ++j) {
        float s = rssq[j];
        s += __shfl_xor(s, 1, 64); s += __shfl_xor(s, 2, 64);
        s += __shfl_xor(s, 4, 64); s += __shfl_xor(s, 8, 64);
        if (ll == 0) {
          const int row = row0 + wr * 64 + mt * 16 + lh * 4 + j;
          DIAG[(((row >> 12) * 16 + hglob) << 12) + (row & 4095)] = HALF_DN2 * s;
        }
      }
    }
  }
}

// ---------------------------------------------------------------------------
// kside5: single-pass online-max K-side. dd split-MFMA -> exp (running max,
// defer THR=4) -> 16x16x16 PV into fp32 partials. Exact global max tracked
// separately (atomicMax). grid 512 = 64 bh x 8 chunks (512 rows), 4 waves.
// ---------------------------------------------------------------------------
__global__ __launch_bounds__(256) void kside5(const ushort_t* __restrict__ KHL,
                                              const ushort_t* __restrict__ VT,
                                              const ushort_t* __restrict__ PHI,
                                              const ushort_t* __restrict__ PLO,
                                              const float* __restrict__ DIAGK,
                                              float* __restrict__ partC,
                                              float* __restrict__ partK,
                                              float* __restrict__ mw,
                                              float* __restrict__ vsum,
                                              unsigned* __restrict__ mxp)
{
  const int tid = threadIdx.x;
  const int l = tid & 63, mg = tid >> 6;
  const int ll = l & 15, lh = l >> 4;
  const int blk = blockIdx.x;
  const int bh = blk >> 3, ck = blk & 7;
  const int b = bh >> 4, h = bh & 15;

  short8 pfh[4][2], pfl[4][2];
  #pragma unroll
  for (int mt = 0; mt < 4; ++mt)
    #pragma unroll
    for (int ks = 0; ks < 2; ++ks) {
      const size_t off = (size_t)(mg * 64 + mt * 16 + ll) * 64 + ks * 32 + lh * 8;
      pfh[mt][ks] = *(const short8*)&PHI[off];
      pfl[mt][ks] = *(const short8*)&PLO[off];
    }

  f32x4 apv[4][4];
  #pragma unroll
  for (int i = 0; i < 4; ++i)
    #pragma unroll
    for (int j = 0; j < 4; ++j) apv[i][j] = (f32x4){0.f, 0.f, 0.f, 0.f};
  float kcp[4] = {0.f, 0.f, 0.f, 0.f};
  float vs[4] = {0.f, 0.f, 0.f, 0.f};
  float m_run = -1.0e30f, tmax = -1.0e30f;

  const int n0 = ck * 512;
  const ushort_t* krow = KHL + ((size_t)(b * NSEQ + n0 + ll) * 16 + h) * 128 + lh * 8;
  const ushort_t* vrow = VT + (size_t)bh * 64 * NSEQ + n0 + lh * 4;
  const float* drow = DIAGK + bh * 4096 + n0 + lh * 4;

  short8 kh0 = *(const short8*)(krow);
  short8 kh1 = *(const short8*)(krow + 32);
  short8 kl0 = *(const short8*)(krow + 64);
  short8 kl1 = *(const short8*)(krow + 96);

  for (int it = 0; it < 32; ++it) {
    short8 nh0, nh1, nl0, nl1;
    if (it < 31) {
      const ushort_t* kp = krow + (size_t)(it + 1) * 16 * 2048;
      nh0 = *(const short8*)(kp);
      nh1 = *(const short8*)(kp + 32);
      nl0 = *(const short8*)(kp + 64);
      nl1 = *(const short8*)(kp + 96);
    }
    const float4 dg4 = *(const float4*)(drow + it * 16);
    short4v vf[4];
    #pragma unroll
    for (int dt = 0; dt < 4; ++dt)
      vf[dt] = *(const short4v*)&vrow[(size_t)(dt * 16 + ll) * NSEQ + it * 16];

    f32x4 dda[4];
    #pragma unroll
    for (int mt = 0; mt < 4; ++mt) {
      f32x4 acc = (f32x4){0.f, 0.f, 0.f, 0.f};
      acc = mfma16(kh0, pfh[mt][0], acc); acc = mfma16(kh1, pfh[mt][1], acc);
      acc = mfma16(kh0, pfl[mt][0], acc); acc = mfma16(kh1, pfl[mt][1], acc);
      acc = mfma16(kl0, pfh[mt][0], acc); acc = mfma16(kl1, pfh[mt][1], acc);
      #pragma unroll
      for (int jr = 0; jr < 4; ++jr) acc[jr] *= DN;
      dda[mt] = acc;
    }

    float pm = -1.0e30f;
    #pragma unroll
    for (int mt = 0; mt < 4; ++mt)
      #pragma unroll
      for (int jr = 0; jr < 4; ++jr) pm = fmaxf(pm, dda[mt][jr]);
    tmax = fmaxf(tmax, pm);
    if (!__all(pm <= m_run + THR_DEFER)) {
      float pw = pm;
      pw = fmaxf(pw, __shfl_xor(pw, 1, 64));  pw = fmaxf(pw, __shfl_xor(pw, 2, 64));
      pw = fmaxf(pw, __shfl_xor(pw, 4, 64));  pw = fmaxf(pw, __shfl_xor(pw, 8, 64));
      pw = fmaxf(pw, __shfl_xor(pw, 16, 64)); pw = fmaxf(pw, __shfl_xor(pw, 32, 64));
      const float sc = __expf(m_run - pw);
      #pragma unroll
      for (int mt = 0; mt < 4; ++mt) {
        kcp[mt] *= sc;
        #pragma unroll
        for (int dt = 0; dt < 4; ++dt) apv[mt][dt] *= sc;
      }
      m_run = pw;
    }

    const float dgv[4] = {dg4.x, dg4.y, dg4.z, dg4.w};
    short4v qa[4];
    #pragma unroll
    for (int mt = 0; mt < 4; ++mt) {
      short4v o;
      float s = 0.f;
      #pragma unroll
      for (int jr = 0; jr < 4; ++jr) {
        const float kv = __expf(dda[mt][jr] - dgv[jr] - m_run);
        const unsigned short ub = f2bf(kv);
        o[jr] = (short)ub;
        s += bf2f(ub);
      }
      qa[mt] = o;
      kcp[mt] += s;
    }

    if (mg == 0) {
      #pragma unroll
      for (int dt = 0; dt < 4; ++dt)
        #pragma unroll
        for (int e = 0; e < 4; ++e) vs[dt] += bf2f((ushort_t)vf[dt][e]);
    }

    #pragma unroll
    for (int dt = 0; dt < 4; ++dt)
      #pragma unroll
      for (int mt = 0; mt < 4; ++mt)
        apv[mt][dt] = mfma16x16(qa[mt], vf[dt], apv[mt][dt]);

    kh0 = nh0; kh1 = nh1; kl0 = nl0; kl1 = nl1;
  }

  // epilogue
  #pragma unroll
  for (int mt = 0; mt < 4; ++mt) {
    float s = kcp[mt];
    s += __shfl_xor(s, 16, 64);
    s += __shfl_xor(s, 32, 64);
    if (lh == 0) partK[blk * 256 + mg * 64 + mt * 16 + ll] = s;
  }
  #pragma unroll
  for (int mt = 0; mt < 4; ++mt)
    #pragma unroll
    for (int dt = 0; dt < 4; ++dt)
      #pragma unroll
      for (int jr = 0; jr < 4; ++jr) {
        const int m = mg * 64 + mt * 16 + lh * 4 + jr;
        const int dh = dt * 16 + ll;
        partC[(size_t)blk * 16384 + (size_t)m * 64 + dh] = apv[mt][dt][jr];
      }
  if (mg == 0) {
    #pragma unroll
    for (int dt = 0; dt < 4; ++dt) {
      float s = vs[dt];
      s += __shfl_xor(s, 16, 64);
      s += __shfl_xor(s, 32, 64);
      if (lh == 0) atomicAdd(&vsum[bh * 64 + dt * 16 + ll], s);
    }
  }
  tmax = fmaxf(tmax, __shfl_xor(tmax, 1, 64));  tmax = fmaxf(tmax, __shfl_xor(tmax, 2, 64));
  tmax = fmaxf(tmax, __shfl_xor(tmax, 4, 64));  tmax = fmaxf(tmax, __shfl_xor(tmax, 8, 64));
  tmax = fmaxf(tmax, __shfl_xor(tmax, 16, 64)); tmax = fmaxf(tmax, __shfl_xor(tmax, 32, 64));
  if (l == 0) {
    atomicMax(mxp, __float_as_uint(tmax));
    mw[blk * 4 + mg] = m_run;
  }
}

// ---------------------------------------------------------------------------
// combine: ctx[m][dh] = ratio*(sum_c e^{mw-MX}*partC + eps*VSUM[dh]);
// kcs[m] = ratio*(sum_c e^{mw-MX}*partK + eps*4096). Writes CTH/CTL [bh][dh][m]
// (hi/lo split) + KCS fp32. grid 256 = 64 bh x 4 m-chunks.
// ---------------------------------------------------------------------------
__global__ __launch_bounds__(256) void combine(const float* __restrict__ partC,
                                               const float* __restrict__ partK,
                                               const float* __restrict__ mw,
                                               const float* __restrict__ vsum,
                                               const unsigned* __restrict__ mxp,
                                               float* __restrict__ KCS,
                                               ushort_t* __restrict__ CTH,
                                               ushort_t* __restrict__ CTL)
{
  const int tid = threadIdx.x;
  const int bh = blockIdx.x >> 2, mc = blockIdx.x & 3;
  const float MX = __uint_as_float(*mxp);
  float s[8];
  #pragma unroll
  for (int c = 0; c < 8; ++c)
    s[c] = RATIO * __expf(mw[(bh * 8 + c) * 4 + mc] - MX);

  __shared__ float ts[64][68];
  const int r = tid >> 4, c4 = (tid & 15) * 4;
  const float reps = RATIO * EPSF;
  const float4 v4 = *(const float4*)&vsum[bh * 64 + c4];
  #pragma unroll
  for (int i = 0; i < 4; ++i) {
    const int ml = r + i * 16;
    float4 a;
    a.x = reps * v4.x; a.y = reps * v4.y; a.z = reps * v4.z; a.w = reps * v4.w;
    #pragma unroll
    for (int c = 0; c < 8; ++c) {
      const float4 p = *(const float4*)&partC[(size_t)(bh * 8 + c) * 16384 +
                                              (size_t)(mc * 64 + ml) * 64 + c4];
      a.x += s[c] * p.x; a.y += s[c] * p.y; a.z += s[c] * p.z; a.w += s[c] * p.w;
    }
    *(float4*)&ts[ml][c4] = a;
  }
  if (tid < 64) {
    const int m = mc * 64 + tid;
    float kv = reps * 4096.0f;
    #pragma unroll
    for (int c = 0; c < 8; ++c) kv += s[c] * partK[(bh * 8 + c) * 256 + m];
    KCS[bh * 256 + m] = kv;
  }
  __syncthreads();
  #pragma unroll
  for (int i = 0; i < 4; ++i) {
    const int dh = r + i * 16;
    ushort4 oh, ol;
    #pragma unroll
    for (int k = 0; k < 4; ++k) {
      const float v = ts[c4 + k][dh];
      const unsigned short hh = f2bf(v);
      ((unsigned short*)&oh)[k] = hh;
      ((unsigned short*)&ol)[k] = f2bf(v - bf2f(hh));
    }
    const size_t o = ((size_t)bh * 64 + dh) * MF + mc * 64 + c4;
    *(ushort4*)&CTH[o] = oh;
    *(ushort4*)&CTL[o] = ol;
  }
}

// ---------------------------------------------------------------------------
// qside6: transposed dd (A=P,B=Q) -> per-lane softmax -> 16x16x16 PV, register
// qp handoff; P/CT/kcs staged once per block. Q from QHL, diag from DIAGQ.
// grid 1024 = 64 bh x 16 tiles (256 rows). 512 thr (8 waves x 2 row-tiles).
// ---------------------------------------------------------------------------
__global__ __launch_bounds__(512, 2) void qside6(const ushort_t* __restrict__ QHL,
                                                 const ushort_t* __restrict__ PHI,
                                                 const ushort_t* __restrict__ PLO,
                                                 const float* __restrict__ DIAGQ,
                                                 const float* __restrict__ kcs,
                                                 const ushort_t* __restrict__ CTH,
                                                 const ushort_t* __restrict__ CTL,
                                                 ushort_t* __restrict__ attb)
{
  extern __shared__ ushort_t lds[];
  ushort_t* pst = lds;            // 32768 ushorts
  ushort_t* ctf = lds + 32768;    // 32768 ushorts
  ushort_t* kcf = lds + 65536;    // 4096 ushorts

  const int tid = threadIdx.x;
  const int l = tid & 63, w = tid >> 6;
  const int ll = l & 15, lh = l >> 4;
  const int bh = blockIdx.x >> 4, qt = blockIdx.x & 15;
  const int b = bh >> 4, h = bh & 15;

  #pragma unroll
  for (int i = 0; i < 8; ++i) {
    const int f = tid + i * 512;
    const int fl = f & 63, r = f >> 6;
    const int p = r & 1, ks = (r >> 1) & 1, mt = r >> 2;
    const ushort_t* src = (p ? PLO : PHI) + (mt * 16 + (fl & 15)) * 64 + ks * 32 + (fl >> 4) * 8;
    *(short8*)&pst[f * 8] = *(const short8*)src;
  }
  #pragma unroll
  for (int i = 0; i < 16; ++i) {
    const int g = tid + i * 512;
    const int gl = g & 63, r = g >> 6;
    const int dt = r & 3, r2 = r >> 2, mt = r2 & 15, p = r2 >> 4;
    const ushort_t* src = (p ? CTL : CTH) +
        ((size_t)bh * 64 + dt * 16 + (gl & 15)) * MF + mt * 16 + (gl >> 4) * 4;
    *(ushort4*)&ctf[g * 4] = *(const ushort4*)src;
  }
  #pragma unroll
  for (int i = 0; i < 2; ++i) {
    const int u = tid + i * 512;
    const int ul = u & 63, mt = u >> 6;
    const int cll = ul & 15, clh = ul >> 4;
    ushort4 o = make_ushort4(0, 0, 0, 0);
    if (cll < 2) {
      #pragma unroll
      for (int e = 0; e < 4; ++e) {
        const float kv = kcs[bh * MF + mt * 16 + clh * 4 + e];
        const unsigned short hi = f2bf(kv);
        ((ushort_t*)&o)[e] = (cll == 0) ? hi : f2bf(kv - bf2f(hi));
      }
    }
    *(ushort4*)&kcf[u * 4] = o;
  }
  __syncthreads();

  const int nloc0 = qt * 256 + w * 32;
  const int rowb0 = b * NSEQ + nloc0;

  short8 qh0[2], ql0[2], qh1[2], ql1[2];
  #pragma unroll
  for (int ks = 0; ks < 2; ++ks) {
    const size_t base = ((size_t)(rowb0 + ll) * 16 + h) * 128 + ks * 32 + lh * 8;
    qh0[ks] = *(const short8*)&QHL[base];
    ql0[ks] = *(const short8*)&QHL[base + 64];
    qh1[ks] = *(const short8*)&QHL[base + (size_t)16 * 2048];
    ql1[ks] = *(const short8*)&QHL[base + (size_t)16 * 2048 + 64];
  }
  const float dg0 = DIAGQ[bh * 4096 + nloc0 + ll];
  const float dg1 = DIAGQ[bh * 4096 + nloc0 + 16 + ll];

  f32x4 dd0[16], dd1[16];
  #pragma unroll
  for (int mt = 0; mt < 16; ++mt) {
    const short8 ph0 = *(const short8*)&pst[((mt * 2 + 0) * 2 + 0) * 512 + l * 8];
    const short8 ph1 = *(const short8*)&pst[((mt * 2 + 1) * 2 + 0) * 512 + l * 8];
    const short8 pl0 = *(const short8*)&pst[((mt * 2 + 0) * 2 + 1) * 512 + l * 8];
    const short8 pl1 = *(const short8*)&pst[((mt * 2 + 1) * 2 + 1) * 512 + l * 8];
    f32x4 a0 = (f32x4){0.f, 0.f, 0.f, 0.f};
    f32x4 a1 = (f32x4){0.f, 0.f, 0.f, 0.f};
    a0 = mfma16(ph0, qh0[0], a0); a0 = mfma16(ph1, qh0[1], a0);
    a0 = mfma16(ph0, ql0[0], a0); a0 = mfma16(ph1, ql0[1], a0);
    a0 = mfma16(pl0, qh0[0], a0); a0 = mfma16(pl1, qh0[1], a0);
    a1 = mfma16(ph0, qh1[0], a1); a1 = mfma16(ph1, qh1[1], a1);
    a1 = mfma16(ph0, ql1[0], a1); a1 = mfma16(ph1, ql1[1], a1);
    a1 = mfma16(pl0, qh1[0], a1); a1 = mfma16(pl1, qh1[1], a1);
    dd0[mt] = a0; dd1[mt] = a1;
  }

  float rm0 = -3.0e38f, rm1 = -3.0e38f;
  #pragma unroll
  for (int mt = 0; mt < 16; ++mt) {
    rm0 = fmaxf(rm0, fmaxf(fmaxf(dd0[mt][0], dd0[mt][1]), fmaxf(dd0[mt][2], dd0[mt][3])));
    rm1 = fmaxf(rm1, fmaxf(fmaxf(dd1[mt][0], dd1[mt][1]), fmaxf(dd1[mt][2], dd1[mt][3])));
  }
  rm0 = fmaxf(rm0, __shfl_xor(rm0, 16, 64)); rm0 = fmaxf(rm0, __shfl_xor(rm0, 32, 64));
  rm1 = fmaxf(rm1, __shfl_xor(rm1, 16, 64)); rm1 = fmaxf(rm1, __shfl_xor(rm1, 32, 64));
  rm0 *= DN; rm1 *= DN;

  short4v qp0[16], qp1[16];
  #pragma unroll
  for (int mt = 0; mt < 16; ++mt) {
    short4v o0, o1;
    #pragma unroll
    for (int jr = 0; jr < 4; ++jr) {
      o0[jr] = (short)f2bf(RATIO * (__expf(dd0[mt][jr] * DN - dg0 - rm0) + EPSF));
      o1[jr] = (short)f2bf(RATIO * (__expf(dd1[mt][jr] * DN - dg1 - rm1) + EPSF));
    }
    qp0[mt] = o0; qp1[mt] = o1;
  }

  f32x4 av0[4], av1[4];
  #pragma unroll
  for (int dt = 0; dt < 4; ++dt) {
    av0[dt] = (f32x4){0.f, 0.f, 0.f, 0.f};
    av1[dt] = (f32x4){0.f, 0.f, 0.f, 0.f};
  }
  f32x4 aK0 = (f32x4){0.f, 0.f, 0.f, 0.f};
  f32x4 aK1 = (f32x4){0.f, 0.f, 0.f, 0.f};
  #pragma unroll
  for (int mt = 0; mt < 16; ++mt) {
    const short4v kcv = *(const short4v*)&kcf[mt * 256 + l * 4];
    aK0 = mfma16x16(qp0[mt], kcv, aK0);
    aK1 = mfma16x16(qp1[mt], kcv, aK1);
    #pragma unroll
    for (int dt = 0; dt < 4; ++dt) {
      const short4v ch = *(const short4v*)&ctf[((0 * 16 + mt) * 4 + dt) * 256 + l * 4];
      const short4v cl = *(const short4v*)&ctf[((16 + mt) * 4 + dt) * 256 + l * 4];
      av0[dt] = mfma16x16(qp0[mt], ch, av0[dt]);
      av0[dt] = mfma16x16(qp0[mt], cl, av0[dt]);
      av1[dt] = mfma16x16(qp1[mt], ch, av1[dt]);
      av1[dt] = mfma16x16(qp1[mt], cl, av1[dt]);
    }
  }

  float di0[4], di1[4];
  #pragma unroll
  for (int jr = 0; jr < 4; ++jr) {
    const float h0 = __shfl(aK0[jr], (l & 48), 64);
    const float l0 = __shfl(aK0[jr], (l & 48) | 1, 64);
    const float h1 = __shfl(aK1[jr], (l & 48), 64);
    const float l1 = __shfl(aK1[jr], (l & 48) | 1, 64);
    di0[jr] = 1.0f / (h0 + l0);
    di1[jr] = 1.0f / (h1 + l1);
  }

  #pragma unroll
  for (int dt = 0; dt < 4; ++dt)
    #pragma unroll
    for (int jr = 0; jr < 4; ++jr) {
      const int col = h * DHD + dt * 16 + ll;
      attb[(size_t)(rowb0 + lh * 4 + jr) * DM + col] = f2bf(av0[dt][jr] * di0[jr]);
      attb[(size_t)(rowb0 + 16 + lh * 4 + jr) * DM + col] = f2bf(av1[dt][jr] * di1[jr]);
    }
}

// ---------------------------------------------------------------------------
extern "C" void kernel_launch(void* const* d_in, const int* in_sizes, int n_in,
                              void* d_out, int out_size, void* d_ws, size_t ws_size,
                              hipStream_t stream)
{
  const float* x  = (const float*)d_in[0];
  const float* Wq = (const float*)d_in[1];
  const float* Wk = (const float*)d_in[2];
  const float* Wv = (const float*)d_in[3];
  const float* Wo = (const float*)d_in[4];
  const float* bo = (const float*)d_in[5];
  const float* P  = (const float*)d_in[6];
  float* out = (float*)d_out;

  char* wp = (char*)d_ws;
  ushort_t* QHL  = (ushort_t*)(wp + 0);            // 64 MB [row][h][128] hi|lo
  ushort_t* KHL  = (ushort_t*)(wp + 67108864);     // 64 MB (ATTB overlays)
  ushort_t* VT   = (ushort_t*)(wp + 134217728);    // 32 MB [bh][dh][n]
  ushort_t* Wqt  = (ushort_t*)(wp + 167772160);
  ushort_t* Wkt  = (ushort_t*)(wp + 169869312);
  ushort_t* Wvt  = (ushort_t*)(wp + 171966464);
  ushort_t* Wot  = (ushort_t*)(wp + 174063616);
  ushort_t* PHI  = (ushort_t*)(wp + 176160768);
  ushort_t* PLO  = (ushort_t*)(wp + 176193536);
  float*    DIAGQ= (float*)(wp + 176226304);       // 1 MB [bh][n]
  float*    DIAGK= (float*)(wp + 177274880);       // 1 MB
  float*    PARTK= (float*)(wp + 178323456);       // 512 KB
  float*    MW   = (float*)(wp + 178847744);       // 8 KB
  float*    VSUM = (float*)(wp + 178855936);       // 16 KB
  unsigned* MX   = (unsigned*)(wp + 178872320);    // 256 B (contiguous w/ VSUM)
  float*    KCS  = (float*)(wp + 178872576);       // 64 KB
  ushort_t* CTH  = (ushort_t*)(wp + 178938112);    // 2 MB
  ushort_t* CTL  = (ushort_t*)(wp + 181035264);    // 2 MB -> end 183132416
  ushort_t* ATTB = KHL;

  // scratch carved out of d_out (fully overwritten by the final Wo-GEMM):
  float*    PARTC= (float*)d_out;                           // 32 MB
  ushort_t* XB   = (ushort_t*)((char*)d_out + 33554432);    // 32 MB

  dim3 tg(16, 16);
  wtrans<<<tg, 256, 0, stream>>>(Wq, Wqt);
  wtrans<<<tg, 256, 0, stream>>>(Wk, Wkt);
  wtrans<<<tg, 256, 0, stream>>>(Wv, Wvt);
  wtrans<<<tg, 256, 0, stream>>>(Wo, Wot);
  psplit<<<64, 256, 0, stream>>>(P, PHI, PLO);
  xconv<<<8192, 256, 0, stream>>>(x, XB);
  hipMemsetAsync(VSUM, 0, 16384 + 256, stream);   // VSUM + MX

  gemm_k<3><<<1024, 256, 0, stream>>>(XB, Wqt, nullptr, nullptr, nullptr, QHL, DIAGQ);
  gemm_k<3><<<1024, 256, 0, stream>>>(XB, Wkt, nullptr, nullptr, nullptr, KHL, DIAGK);
  gemm_k<2><<<1024, 256, 0, stream>>>(XB, Wvt, nullptr, nullptr, VT, nullptr, nullptr);

  kside5<<<512, 256, 0, stream>>>(KHL, VT, PHI, PLO, DIAGK, PARTC, PARTK, MW, VSUM, MX);
  combine<<<256, 256, 0, stream>>>(PARTC, PARTK, MW, VSUM, MX, KCS, CTH, CTL);
  qside6<<<1024, 512, 139264, stream>>>(QHL, PHI, PLO, DIAGQ, KCS, CTH, CTL, ATTB);

  gemm_k<1><<<1024, 256, 0, stream>>>(ATTB, Wot, bo, out, nullptr, nullptr, nullptr);
}